// Round 3
// baseline (170.972 us; speedup 1.0000x reference)
//
#include <hip/hip_runtime.h>
#include <math.h>

#define N_NODES 2048
#define T_WIN 5
#define D_EMB 64
#define TOPK 21
#define B_BATCH 32
#define BN_TOTAL (B_BATCH * N_NODES)   // 65536
#define EPS_BN 1e-5f
#define NEG_SLOPE 0.2f
#define STATS_STRIDE 16

typedef unsigned long long u64;

// ---------------- wave-level helpers (wave = 64 on gfx950) ----------------
__device__ __forceinline__ float wave_sum(float v) {
#pragma unroll
    for (int off = 32; off > 0; off >>= 1) v += __shfl_xor(v, off, 64);
    return v;
}

__device__ __forceinline__ u64 max64(u64 a, u64 b) { return a > b ? a : b; }
__device__ __forceinline__ u64 min64(u64 a, u64 b) { return a < b ? a : b; }

__device__ __forceinline__ u64 bitonic_sort64_desc(u64 key, int lane) {
#pragma unroll
    for (int k = 2; k <= 64; k <<= 1) {
#pragma unroll
        for (int j = k >> 1; j >= 1; j >>= 1) {
            u64 pk = __shfl_xor(key, j, 64);
            bool dirDesc = ((lane & k) == 0);
            bool keepMax = (((lane & j) == 0) == dirDesc);
            key = keepMax ? max64(key, pk) : min64(key, pk);
        }
    }
    return key;
}

__device__ __forceinline__ u64 bitonic_merge_top64(u64 a, u64 b, int lane) {
    u64 br = __shfl(b, 63 - lane, 64);
    u64 c = max64(a, br);
#pragma unroll
    for (int j = 32; j >= 1; j >>= 1) {
        u64 pk = __shfl_xor(c, j, 64);
        bool keepMax = ((lane & j) == 0);
        c = keepMax ? max64(c, pk) : min64(c, pk);
    }
    return c;
}

// ---------------- K1: k_pre — fused edge + gram (independent work) ----------
// Blocks 0..527: Gram upper-triangle tiles writing RAW dot products (the
// /(ni*nj) moved to k_select — same operands, same IEEE '/', bit-identical
// cos keys). This removes gram's dependency on norms, so the edge work
// (es/ed/norms, unchanged arithmetic) rides in the same dispatch as blocks
// 528..783 and overlaps gram's VALU-heavy tiles. One fewer launch boundary.
__global__ __launch_bounds__(256) void k_pre(
    const float* __restrict__ x, const float* __restrict__ W,
    const float* __restrict__ Wb, const float* __restrict__ a_src,
    const float* __restrict__ a_dst, const float* __restrict__ emb,
    float* __restrict__ es2T, float* __restrict__ ed2T,
    float* __restrict__ norms, float* __restrict__ dotM,
    float* __restrict__ stats, float* __restrict__ stats2) {
    if (blockIdx.x >= 528) {
        // ---- edge path: es2T/ed2T [b][n] + norms + stats zero ----
        int eb = blockIdx.x - 528;                 // 0..255
        if (eb < 2) {
            float* p = eb ? stats2 : stats;
            ((float4*)p)[threadIdx.x] = make_float4(0.f, 0.f, 0.f, 0.f);
        }
        int wid = threadIdx.x >> 6, lane = threadIdx.x & 63;
        int gw = eb * 4 + wid;                     // 0..1023
        const float* wp = W + lane * T_WIN;
        float w0 = wp[0], w1 = wp[1], w2 = wp[2], w3 = wp[3], w4 = wp[4];
        float bias = Wb[lane];
        float as = a_src[lane], asE = a_src[D_EMB + lane];
        float ad = a_dst[lane], adE = a_dst[D_EMB + lane];

        for (int node = gw; node < BN_TOTAL; node += 1024) {
            int n = node & (N_NODES - 1);
            const float* xp = x + (size_t)node * T_WIN;
            float hv = bias + xp[0] * w0 + xp[1] * w1 + xp[2] * w2 + xp[3] * w3 + xp[4] * w4;
            float e = emb[n * D_EMB + lane];
            if (node < N_NODES) {                  // b==0 pass: emit norms
                float s2 = wave_sum(e * e);
                if (lane == 0) norms[node] = sqrtf(s2);
            }
            float es = wave_sum(hv * as + e * asE);
            float ed = wave_sum(hv * ad + e * adE);
            if (lane == 0) {
                es2T[node] = es;   // node = b*N + n  -> [b][n] layout
                ed2T[node] = ed;
            }
        }
        return;
    }

    // ---- gram path: raw Gram tile, symmetric write (dot is exact-symmetric)
    __shared__ __align__(16) float As[64][68];   // [d][i]
    __shared__ __align__(16) float Bs[64][68];   // [d][j]
    int t = threadIdx.x;
    int g = blockIdx.x;                          // 0..527
    int a = (int)((sqrtf(8.f * g + 1.f) - 1.f) * 0.5f);
    while ((a + 1) * (a + 2) / 2 <= g) a++;
    while (a * (a + 1) / 2 > g) a--;
    int bq = g - a * (a + 1) / 2;                // 0..a
    int i0 = a * 64, j0 = bq * 64;

    {
        int r = t >> 2, c0 = t & 3;
        const float4* srcA = (const float4*)(emb + (size_t)(i0 + r) * D_EMB);
        const float4* srcB = (const float4*)(emb + (size_t)(j0 + r) * D_EMB);
#pragma unroll
        for (int k = 0; k < 4; k++) {
            int f4 = c0 + 4 * k;
            float4 v = srcA[f4];
            int d = 4 * f4;
            As[d][r] = v.x; As[d + 1][r] = v.y; As[d + 2][r] = v.z; As[d + 3][r] = v.w;
            float4 w = srcB[f4];
            Bs[d][r] = w.x; Bs[d + 1][r] = w.y; Bs[d + 2][r] = w.z; Bs[d + 3][r] = w.w;
        }
    }
    __syncthreads();

    int ti = t & 15, tj = t >> 4;
    float acc[4][4] = {};
#pragma unroll
    for (int d = 0; d < 64; d++) {
        float4 av = *(const float4*)&As[d][4 * ti];
        float4 bv = *(const float4*)&Bs[d][4 * tj];
        acc[0][0] += av.x * bv.x; acc[0][1] += av.x * bv.y; acc[0][2] += av.x * bv.z; acc[0][3] += av.x * bv.w;
        acc[1][0] += av.y * bv.x; acc[1][1] += av.y * bv.y; acc[1][2] += av.y * bv.z; acc[1][3] += av.y * bv.w;
        acc[2][0] += av.z * bv.x; acc[2][1] += av.z * bv.y; acc[2][2] += av.z * bv.z; acc[2][3] += av.z * bv.w;
        acc[3][0] += av.w * bv.x; acc[3][1] += av.w * bv.y; acc[3][2] += av.w * bv.z; acc[3][3] += av.w * bv.w;
    }

#pragma unroll
    for (int r = 0; r < 4; r++) {
        float4 o;
        o.x = acc[r][0]; o.y = acc[r][1]; o.z = acc[r][2]; o.w = acc[r][3];
        int i = i0 + 4 * ti + r;
        *(float4*)(dotM + (size_t)i * N_NODES + j0 + 4 * tj) = o;
        dotM[(size_t)(j0 + 4 * tj + 0) * N_NODES + i] = o.x;
        dotM[(size_t)(j0 + 4 * tj + 1) * N_NODES + i] = o.y;
        dotM[(size_t)(j0 + 4 * tj + 2) * N_NODES + i] = o.z;
        dotM[(size_t)(j0 + 4 * tj + 3) * N_NODES + i] = o.w;
    }
}

// ---------------- K2: top-21 selection -> idxT[k][i] ------------------------
// Normalizes on the fly: v = dot/(ni*nj) with the SAME operands and IEEE '/'
// the old k_gram used -> key bits identical -> selection identical.
__global__ __launch_bounds__(256) void k_select(
    const float* __restrict__ dotM, const float* __restrict__ norms,
    int* __restrict__ idxT) {
    __shared__ u64 candbuf[4][128];
    int tid = threadIdx.x;
    int wid = tid >> 6, lane = tid & 63;
    int i = blockIdx.x * 4 + wid;
    const float* row = dotM + (size_t)i * N_NODES;
    u64* buf = candbuf[wid];
    float ni = norms[i];

    u64 a = 0;
    u64 t = 0;
    int cnt = 0;
    float vcur = row[lane];
    float ncur = norms[lane];

#pragma unroll 1
    for (int c = 0; c < N_NODES / 64; c++) {
        int j = c * 64 + lane;
        float dv = vcur, nv = ncur;
        if (c < N_NODES / 64 - 1) { vcur = row[j + 64]; ncur = norms[j + 64]; }
        float v = dv / (ni * nv);
        unsigned u = __float_as_uint(v);
        u = (u & 0x80000000u) ? ~u : (u | 0x80000000u);
        u64 key = ((u64)u << 32) | (unsigned)(~j);
        unsigned long long ball = __ballot(key > t);
        if (ball) {
            int ofs = __popcll(ball & ((1ull << lane) - 1ull));
            if (key > t) buf[cnt + ofs] = key;
            cnt += (int)__popcll(ball);
            if (cnt >= 64) {
                u64 nk = buf[lane];
                nk = bitonic_sort64_desc(nk, lane);
                a = bitonic_merge_top64(a, nk, lane);
                t = __shfl(a, 20, 64);
                int rem = cnt - 64;
                u64 mv = (lane < rem) ? buf[64 + lane] : 0;
                if (lane < rem) buf[lane] = mv;
                cnt = rem;
            }
        }
    }
    while (cnt > 0) {
        int take = cnt < 64 ? cnt : 64;
        u64 nk = (lane < take) ? buf[lane] : 0;
        nk = bitonic_sort64_desc(nk, lane);
        a = bitonic_merge_top64(a, nk, lane);
        t = __shfl(a, 20, 64);
        int rem = cnt - take;
        u64 mv = (lane < rem) ? buf[take + lane] : 0;
        if (lane < rem) buf[lane] = mv;
        cnt = rem;
    }

    if (lane < TOPK) idxT[lane * N_NODES + i] = (int)(~(unsigned)a);
}

// ---------------- K3: k_alpha — softmax -> packed paT[b][k][i]={alpha,idx} --
// Packing alpha+idx into one float2 record halves k_msg's global-load issue
// count (42 -> 21 instrs/item) and drops idxT from its working set.
__global__ __launch_bounds__(256) void k_alpha(
    const int* __restrict__ idxT, const float* __restrict__ es2T,
    const float* __restrict__ ed2T, float2* __restrict__ paT) {
    __shared__ float sed[N_NODES];   // 8 KB
    int g = blockIdx.x;
    int b = g & 31;
    int i0 = (g >> 5) * 256;
    int t = threadIdx.x;

    {
        const float4* src = (const float4*)(ed2T + (size_t)b * N_NODES);
        float4* dst = (float4*)sed;
#pragma unroll
        for (int q = 0; q < 2; q++) dst[t + 256 * q] = src[t + 256 * q];
    }
    __syncthreads();

    int i = i0 + t;
    float es = es2T[(size_t)b * N_NODES + i];
    int jk[TOPK];
    float ev[TOPK];
    float m = -3e38f;
#pragma unroll
    for (int k = 0; k < TOPK; k++) {
        jk[k] = idxT[k * N_NODES + i];
        float e = es + sed[jk[k]];
        e = e > 0.f ? e : NEG_SLOPE * e;
        ev[k] = e;
        m = fmaxf(m, e);
    }
    float s = 0.f;
#pragma unroll
    for (int k = 0; k < TOPK; k++) {
        ev[k] = __expf(ev[k] - m);
        s += ev[k];
    }
    float inv = 1.0f / s;
#pragma unroll
    for (int k = 0; k < TOPK; k++) {
        float2 v;
        v.x = ev[k] * inv;
        v.y = __int_as_float(jk[k]);
        paT[((size_t)b * TOPK + k) * N_NODES + i] = v;
    }
}

// ---------------- K4: message passing — LDS h-tile, packed pa loads ---------
// Block = (b, d-chunk of 4). h-tile built from x in-LDS. Gather: one b64
// global load (alpha+idx packed) + 2x ds_read_b64 + 4 FMA per neighbor.
// [R1 post-mortem: k_msg is LDS/VMEM-issue-throughput bound — the packed
// load halves VMEM issue+address VALU vs separate idxT/alphaT streams.]
__global__ __launch_bounds__(256, 2) void k_msg(
    const float* __restrict__ x, const float* __restrict__ W,
    const float* __restrict__ Wb, const float2* __restrict__ paT,
    const float* __restrict__ emb, float* __restrict__ obufT,
    float* __restrict__ stats, float* __restrict__ stats2) {
    __shared__ float hts[N_NODES][6];          // 48 KB, stride 24 B
    __shared__ float sred[2][4][4];

    int g = blockIdx.x;                        // 512 = 32 b x 16 c
    int b = (g & 7) + 8 * ((g >> 3) & 3);      // XCD-local batches
    int c = g >> 5;
    int d0 = c * 4;
    int t = threadIdx.x;
    int wid = t >> 6, lane = t & 63;

    // ---- build h-tile from x ----
    float wc[4][T_WIN], wb4[4];
#pragma unroll
    for (int q = 0; q < 4; q++) {
        wb4[q] = Wb[d0 + q];
#pragma unroll
        for (int tt = 0; tt < T_WIN; tt++) wc[q][tt] = W[(d0 + q) * T_WIN + tt];
    }
    const float* xb = x + (size_t)b * N_NODES * T_WIN;
#pragma unroll
    for (int r = 0; r < 8; r++) {
        int row = t + 256 * r;
        const float* xr = xb + row * T_WIN;
        float x0 = xr[0], x1 = xr[1], x2 = xr[2], x3 = xr[3], x4 = xr[4];
        float h0 = wb4[0] + x0 * wc[0][0] + x1 * wc[0][1] + x2 * wc[0][2] + x3 * wc[0][3] + x4 * wc[0][4];
        float h1 = wb4[1] + x0 * wc[1][0] + x1 * wc[1][1] + x2 * wc[1][2] + x3 * wc[1][3] + x4 * wc[1][4];
        float h2 = wb4[2] + x0 * wc[2][0] + x1 * wc[2][1] + x2 * wc[2][2] + x3 * wc[2][3] + x4 * wc[2][4];
        float h3 = wb4[3] + x0 * wc[3][0] + x1 * wc[3][1] + x2 * wc[3][2] + x3 * wc[3][3] + x4 * wc[3][4];
        *(float2*)&hts[row][0] = make_float2(h0, h1);
        *(float2*)&hts[row][2] = make_float2(h2, h3);
    }
    __syncthreads();

    // ---- gather: 2048 items, 8 per thread ----
    float sacc[4] = {0.f, 0.f, 0.f, 0.f};
    float sacc2[4] = {0.f, 0.f, 0.f, 0.f};
    const float2* pb = paT + (size_t)b * TOPK * N_NODES;
#pragma unroll 1
    for (int r = 0; r < 8; r++) {
        int i = 256 * r + t;
        float4 z = make_float4(0.f, 0.f, 0.f, 0.f);
#pragma unroll
        for (int k = 0; k < TOPK; k++) {
            float2 pa = pb[(size_t)k * N_NODES + i];   // coalesced b64
            int jk = __float_as_int(pa.y);
            float a = pa.x;
            float2 h01 = *(const float2*)&hts[jk][0];
            float2 h23 = *(const float2*)&hts[jk][2];
            z.x = fmaf(a, h01.x, z.x);
            z.y = fmaf(a, h01.y, z.y);
            z.z = fmaf(a, h23.x, z.z);
            z.w = fmaf(a, h23.y, z.w);
        }
        float4 e4 = *(const float4*)(emb + (size_t)i * D_EMB + d0);
        float4 o;
        o.x = fmaxf(z.x, 0.f) * e4.x;
        o.y = fmaxf(z.y, 0.f) * e4.y;
        o.z = fmaxf(z.z, 0.f) * e4.z;
        o.w = fmaxf(z.w, 0.f) * e4.w;
        ((float4*)obufT)[((size_t)c * B_BATCH + b) * N_NODES + i] = o;
        sacc[0] += o.x; sacc[1] += o.y; sacc[2] += o.z; sacc[3] += o.w;
        sacc2[0] += o.x * o.x; sacc2[1] += o.y * o.y;
        sacc2[2] += o.z * o.z; sacc2[3] += o.w * o.w;
    }

    // ---- stats partials ----
#pragma unroll
    for (int q = 0; q < 4; q++) {
        sacc[q] = wave_sum(sacc[q]);
        sacc2[q] = wave_sum(sacc2[q]);
    }
    if (lane == 0) {
#pragma unroll
        for (int q = 0; q < 4; q++) {
            sred[0][wid][q] = sacc[q];
            sred[1][wid][q] = sacc2[q];
        }
    }
    __syncthreads();
    if (t < 8) {
        int q = t & 3, which = t >> 2;
        float v = sred[which][0][q] + sred[which][1][q] + sred[which][2][q] + sred[which][3][q];
        float* dst = which ? stats2 : stats;
        atomicAdd(&dst[(d0 + q) * STATS_STRIDE], v);
    }
}

// ---------------- K5: BN apply + relu + fc — coalesced c-panel sweep --------
__global__ __launch_bounds__(256) void k_out(
    const float* __restrict__ obufT, const float* __restrict__ stats,
    const float* __restrict__ stats2, const float* __restrict__ gamma,
    const float* __restrict__ beta, const float* __restrict__ fc_w,
    const float* __restrict__ fc_b, float* __restrict__ out) {
    __shared__ float smean[64], sinv[64], sg[64], sb[64], sf[64];
    int t = threadIdx.x;
    int g = blockIdx.x;                 // 256 = 32 b x 8 n-chunks
    int b = g & 31, nc = g >> 5;
    int n = nc * 256 + t;
    const float invM = 1.0f / (float)BN_TOTAL;

    if (t < 64) {
        float mn = stats[t * STATS_STRIDE] * invM;
        float var = stats2[t * STATS_STRIDE] * invM - mn * mn;
        smean[t] = mn;
        sinv[t] = rsqrtf(var + EPS_BN);
        sg[t] = gamma[t]; sb[t] = beta[t]; sf[t] = fc_w[t];
    }
    __syncthreads();

    float fb = fc_b[0];
    float p = 0.f;
#pragma unroll
    for (int c = 0; c < 16; c++) {
        float4 o = ((const float4*)obufT)[((size_t)c * B_BATCH + b) * N_NODES + n];
        int d = 4 * c;
        float v;
        v = fmaxf((o.x - smean[d + 0]) * sinv[d + 0] * sg[d + 0] + sb[d + 0], 0.f); p = fmaf(v, sf[d + 0], p);
        v = fmaxf((o.y - smean[d + 1]) * sinv[d + 1] * sg[d + 1] + sb[d + 1], 0.f); p = fmaf(v, sf[d + 1], p);
        v = fmaxf((o.z - smean[d + 2]) * sinv[d + 2] * sg[d + 2] + sb[d + 2], 0.f); p = fmaf(v, sf[d + 2], p);
        v = fmaxf((o.w - smean[d + 3]) * sinv[d + 3] * sg[d + 3] + sb[d + 3], 0.f); p = fmaf(v, sf[d + 3], p);
    }
    out[b * N_NODES + n] = p + fb;
}

// ---------------- launch ----------------------------------------------------
extern "C" void kernel_launch(void* const* d_in, const int* in_sizes, int n_in,
                              void* d_out, int out_size, void* d_ws, size_t ws_size,
                              hipStream_t stream) {
    const float* x     = (const float*)d_in[0];
    const float* emb   = (const float*)d_in[1];
    const float* W     = (const float*)d_in[2];
    const float* Wb    = (const float*)d_in[3];
    const float* a_src = (const float*)d_in[4];
    const float* a_dst = (const float*)d_in[5];
    const float* gamma = (const float*)d_in[6];
    const float* beta  = (const float*)d_in[7];
    const float* fc_w  = (const float*)d_in[8];
    const float* fc_b  = (const float*)d_in[9];
    float* out = (float*)d_out;

    char* ws = (char*)d_ws;
    float*  stats  = (float*) (ws + 0);            // 4 KB
    float*  stats2 = (float*) (ws + 4096);         // 4 KB
    int*    idxT   = (int*)   (ws + 8192);         // 172032 B
    float*  norms  = (float*) (ws + 180224);       // 8 KB
    float*  es2T   = (float*) (ws + 188416);       // 256 KB [b][n]
    float*  ed2T   = (float*) (ws + 450560);       // 256 KB [b][n]
    float2* paT    = (float2*)(ws + 712704);       // 11010048 B [b][k][i] packed
    float*  dotM   = (float*) (ws + 11722752);     // 16 MB — aliased with obufT
    float*  obufT  = dotM;                         // (dotM dead after k_select)
    // total: 28,499,968 bytes

    k_pre<<<784, 256, 0, stream>>>(x, W, Wb, a_src, a_dst, emb,
                                   es2T, ed2T, norms, dotM, stats, stats2);
    k_select<<<N_NODES / 4, 256, 0, stream>>>(dotM, norms, idxT);
    k_alpha<<<256, 256, 0, stream>>>(idxT, es2T, ed2T, paT);
    k_msg<<<512, 256, 0, stream>>>(x, W, Wb, paT, emb, obufT, stats, stats2);
    k_out<<<256, 256, 0, stream>>>(obufT, stats, stats2, gamma, beta, fc_w, fc_b, out);
}

// Round 4
// 148.745 us; speedup vs baseline: 1.1494x; 1.1494x over previous
//
#include <hip/hip_runtime.h>
#include <math.h>

#define N_NODES 2048
#define T_WIN 5
#define D_EMB 64
#define TOPK 21
#define B_BATCH 32
#define BN_TOTAL (B_BATCH * N_NODES)   // 65536
#define EPS_BN 1e-5f
#define NEG_SLOPE 0.2f
#define STATS_STRIDE 16

typedef unsigned long long u64;

// ---------------- wave-level helpers (wave = 64 on gfx950) ----------------
__device__ __forceinline__ float wave_sum(float v) {
#pragma unroll
    for (int off = 32; off > 0; off >>= 1) v += __shfl_xor(v, off, 64);
    return v;
}

__device__ __forceinline__ u64 max64(u64 a, u64 b) { return a > b ? a : b; }
__device__ __forceinline__ u64 min64(u64 a, u64 b) { return a < b ? a : b; }

__device__ __forceinline__ u64 bitonic_sort64_desc(u64 key, int lane) {
#pragma unroll
    for (int k = 2; k <= 64; k <<= 1) {
#pragma unroll
        for (int j = k >> 1; j >= 1; j >>= 1) {
            u64 pk = __shfl_xor(key, j, 64);
            bool dirDesc = ((lane & k) == 0);
            bool keepMax = (((lane & j) == 0) == dirDesc);
            key = keepMax ? max64(key, pk) : min64(key, pk);
        }
    }
    return key;
}

__device__ __forceinline__ u64 bitonic_merge_top64(u64 a, u64 b, int lane) {
    u64 br = __shfl(b, 63 - lane, 64);
    u64 c = max64(a, br);
#pragma unroll
    for (int j = 32; j >= 1; j >>= 1) {
        u64 pk = __shfl_xor(c, j, 64);
        bool keepMax = ((lane & j) == 0);
        c = keepMax ? max64(c, pk) : min64(c, pk);
    }
    return c;
}

// ---------------- K1: k_edge — es2T/ed2T [b][n] + norms + stats zero --------
// [R3 post-mortem: fusing this with gram collapsed edge TLP 8x (8192->1024
// waves) and went latency-bound (VALUBusy 10%, 46-53 us). Grid shape is
// sacred on this latency-bound serial-shfl kernel: 2048 blocks, 8 items/wave.]
__global__ __launch_bounds__(256) void k_edge(
    const float* __restrict__ x, const float* __restrict__ W,
    const float* __restrict__ Wb, const float* __restrict__ a_src,
    const float* __restrict__ a_dst, const float* __restrict__ emb,
    float* __restrict__ es2T, float* __restrict__ ed2T,
    float* __restrict__ norms, float* __restrict__ stats,
    float* __restrict__ stats2) {
    if (blockIdx.x < 2) {
        float* p = blockIdx.x ? stats2 : stats;
        ((float4*)p)[threadIdx.x] = make_float4(0.f, 0.f, 0.f, 0.f);
    }
    int wid = threadIdx.x >> 6, lane = threadIdx.x & 63;
    int gw = blockIdx.x * 4 + wid;
    const float* wp = W + lane * T_WIN;
    float w0 = wp[0], w1 = wp[1], w2 = wp[2], w3 = wp[3], w4 = wp[4];
    float bias = Wb[lane];
    float as = a_src[lane], asE = a_src[D_EMB + lane];
    float ad = a_dst[lane], adE = a_dst[D_EMB + lane];

    for (int node = gw; node < BN_TOTAL; node += 8192) {
        int n = node & (N_NODES - 1);
        const float* xp = x + (size_t)node * T_WIN;
        float hv = bias + xp[0] * w0 + xp[1] * w1 + xp[2] * w2 + xp[3] * w3 + xp[4] * w4;
        float e = emb[n * D_EMB + lane];
        if (node < N_NODES) {                   // b==0 pass: also emit norms
            float s2 = wave_sum(e * e);
            if (lane == 0) norms[node] = sqrtf(s2);
        }
        float es = wave_sum(hv * as + e * asE);
        float ed = wave_sum(hv * ad + e * adE);
        if (lane == 0) {
            es2T[node] = es;   // node = b*N + n  -> [b][n] layout
            ed2T[node] = ed;
        }
    }
}

// ---------------- K2a: Gram/cos — upper-triangle blocks, symmetric write ----
__global__ __launch_bounds__(256) void k_gram(
    const float* __restrict__ emb, const float* __restrict__ norms,
    float* __restrict__ cosM) {
    __shared__ __align__(16) float As[64][68];   // [d][i]
    __shared__ __align__(16) float Bs[64][68];   // [d][j]
    int t = threadIdx.x;
    int g = blockIdx.x;                          // 0..527
    int a = (int)((sqrtf(8.f * g + 1.f) - 1.f) * 0.5f);
    while ((a + 1) * (a + 2) / 2 <= g) a++;
    while (a * (a + 1) / 2 > g) a--;
    int bq = g - a * (a + 1) / 2;                // 0..a
    int i0 = a * 64, j0 = bq * 64;

    {
        int r = t >> 2, c0 = t & 3;
        const float4* srcA = (const float4*)(emb + (size_t)(i0 + r) * D_EMB);
        const float4* srcB = (const float4*)(emb + (size_t)(j0 + r) * D_EMB);
#pragma unroll
        for (int k = 0; k < 4; k++) {
            int f4 = c0 + 4 * k;
            float4 v = srcA[f4];
            int d = 4 * f4;
            As[d][r] = v.x; As[d + 1][r] = v.y; As[d + 2][r] = v.z; As[d + 3][r] = v.w;
            float4 w = srcB[f4];
            Bs[d][r] = w.x; Bs[d + 1][r] = w.y; Bs[d + 2][r] = w.z; Bs[d + 3][r] = w.w;
        }
    }
    __syncthreads();

    int ti = t & 15, tj = t >> 4;
    float acc[4][4] = {};
#pragma unroll
    for (int d = 0; d < 64; d++) {
        float4 av = *(const float4*)&As[d][4 * ti];
        float4 bv = *(const float4*)&Bs[d][4 * tj];
        acc[0][0] += av.x * bv.x; acc[0][1] += av.x * bv.y; acc[0][2] += av.x * bv.z; acc[0][3] += av.x * bv.w;
        acc[1][0] += av.y * bv.x; acc[1][1] += av.y * bv.y; acc[1][2] += av.y * bv.z; acc[1][3] += av.y * bv.w;
        acc[2][0] += av.z * bv.x; acc[2][1] += av.z * bv.y; acc[2][2] += av.z * bv.z; acc[2][3] += av.z * bv.w;
        acc[3][0] += av.w * bv.x; acc[3][1] += av.w * bv.y; acc[3][2] += av.w * bv.z; acc[3][3] += av.w * bv.w;
    }

    float nis[4] = {norms[i0 + 4 * ti], norms[i0 + 4 * ti + 1],
                    norms[i0 + 4 * ti + 2], norms[i0 + 4 * ti + 3]};
    float njs[4] = {norms[j0 + 4 * tj], norms[j0 + 4 * tj + 1],
                    norms[j0 + 4 * tj + 2], norms[j0 + 4 * tj + 3]};
#pragma unroll
    for (int r = 0; r < 4; r++) {
        float4 o;
        o.x = acc[r][0] / (nis[r] * njs[0]);
        o.y = acc[r][1] / (nis[r] * njs[1]);
        o.z = acc[r][2] / (nis[r] * njs[2]);
        o.w = acc[r][3] / (nis[r] * njs[3]);
        int i = i0 + 4 * ti + r;
        *(float4*)(cosM + (size_t)i * N_NODES + j0 + 4 * tj) = o;
        cosM[(size_t)(j0 + 4 * tj + 0) * N_NODES + i] = o.x;
        cosM[(size_t)(j0 + 4 * tj + 1) * N_NODES + i] = o.y;
        cosM[(size_t)(j0 + 4 * tj + 2) * N_NODES + i] = o.z;
        cosM[(size_t)(j0 + 4 * tj + 3) * N_NODES + i] = o.w;
    }
}

// ---------------- K2b: top-21 selection -> idxT[k][i] (transposed) ----------
__global__ __launch_bounds__(256) void k_select(
    const float* __restrict__ cosM, int* __restrict__ idxT) {
    __shared__ u64 candbuf[4][128];
    int tid = threadIdx.x;
    int wid = tid >> 6, lane = tid & 63;
    int i = blockIdx.x * 4 + wid;
    const float* row = cosM + (size_t)i * N_NODES;
    u64* buf = candbuf[wid];

    u64 a = 0;
    u64 t = 0;
    int cnt = 0;
    float vcur = row[lane];

#pragma unroll 1
    for (int c = 0; c < N_NODES / 64; c++) {
        int j = c * 64 + lane;
        float v = vcur;
        if (c < N_NODES / 64 - 1) vcur = row[j + 64];
        unsigned u = __float_as_uint(v);
        u = (u & 0x80000000u) ? ~u : (u | 0x80000000u);
        u64 key = ((u64)u << 32) | (unsigned)(~j);
        unsigned long long ball = __ballot(key > t);
        if (ball) {
            int ofs = __popcll(ball & ((1ull << lane) - 1ull));
            if (key > t) buf[cnt + ofs] = key;
            cnt += (int)__popcll(ball);
            if (cnt >= 64) {
                u64 nk = buf[lane];
                nk = bitonic_sort64_desc(nk, lane);
                a = bitonic_merge_top64(a, nk, lane);
                t = __shfl(a, 20, 64);
                int rem = cnt - 64;
                u64 mv = (lane < rem) ? buf[64 + lane] : 0;
                if (lane < rem) buf[lane] = mv;
                cnt = rem;
            }
        }
    }
    while (cnt > 0) {
        int take = cnt < 64 ? cnt : 64;
        u64 nk = (lane < take) ? buf[lane] : 0;
        nk = bitonic_sort64_desc(nk, lane);
        a = bitonic_merge_top64(a, nk, lane);
        t = __shfl(a, 20, 64);
        int rem = cnt - take;
        u64 mv = (lane < rem) ? buf[take + lane] : 0;
        if (lane < rem) buf[lane] = mv;
        cnt = rem;
    }

    if (lane < TOPK) idxT[lane * N_NODES + i] = (int)(~(unsigned)a);
}

// ---------------- K3: k_alpha — softmax -> packed paT[b][k][i]={alpha,idx} --
// Packing alpha+idx into one float2 record halves k_msg's global-load issue
// count (42 -> 21 instrs/item) and drops idxT from its working set.
__global__ __launch_bounds__(256) void k_alpha(
    const int* __restrict__ idxT, const float* __restrict__ es2T,
    const float* __restrict__ ed2T, float2* __restrict__ paT) {
    __shared__ float sed[N_NODES];   // 8 KB
    int g = blockIdx.x;
    int b = g & 31;
    int i0 = (g >> 5) * 256;
    int t = threadIdx.x;

    {
        const float4* src = (const float4*)(ed2T + (size_t)b * N_NODES);
        float4* dst = (float4*)sed;
#pragma unroll
        for (int q = 0; q < 2; q++) dst[t + 256 * q] = src[t + 256 * q];
    }
    __syncthreads();

    int i = i0 + t;
    float es = es2T[(size_t)b * N_NODES + i];
    int jk[TOPK];
    float ev[TOPK];
    float m = -3e38f;
#pragma unroll
    for (int k = 0; k < TOPK; k++) {
        jk[k] = idxT[k * N_NODES + i];
        float e = es + sed[jk[k]];
        e = e > 0.f ? e : NEG_SLOPE * e;
        ev[k] = e;
        m = fmaxf(m, e);
    }
    float s = 0.f;
#pragma unroll
    for (int k = 0; k < TOPK; k++) {
        ev[k] = __expf(ev[k] - m);
        s += ev[k];
    }
    float inv = 1.0f / s;
#pragma unroll
    for (int k = 0; k < TOPK; k++) {
        float2 v;
        v.x = ev[k] * inv;
        v.y = __int_as_float(jk[k]);
        paT[((size_t)b * TOPK + k) * N_NODES + i] = v;
    }
}

// ---------------- K4: message passing — LDS h-tile, packed pa loads ---------
// Block = (b, d-chunk of 4). h-tile built from x in-LDS. Gather: one b64
// global load (alpha+idx packed) + 2x ds_read_b64 + 4 FMA per neighbor.
// [R1 post-mortem: k_msg is LDS/VMEM-issue-throughput bound — the packed
// load halves VMEM issue+address VALU vs separate idxT/alphaT streams.]
__global__ __launch_bounds__(256, 2) void k_msg(
    const float* __restrict__ x, const float* __restrict__ W,
    const float* __restrict__ Wb, const float2* __restrict__ paT,
    const float* __restrict__ emb, float* __restrict__ obufT,
    float* __restrict__ stats, float* __restrict__ stats2) {
    __shared__ float hts[N_NODES][6];          // 48 KB, stride 24 B
    __shared__ float sred[2][4][4];

    int g = blockIdx.x;                        // 512 = 32 b x 16 c
    int b = (g & 7) + 8 * ((g >> 3) & 3);      // XCD-local batches
    int c = g >> 5;
    int d0 = c * 4;
    int t = threadIdx.x;
    int wid = t >> 6, lane = t & 63;

    // ---- build h-tile from x ----
    float wc[4][T_WIN], wb4[4];
#pragma unroll
    for (int q = 0; q < 4; q++) {
        wb4[q] = Wb[d0 + q];
#pragma unroll
        for (int tt = 0; tt < T_WIN; tt++) wc[q][tt] = W[(d0 + q) * T_WIN + tt];
    }
    const float* xb = x + (size_t)b * N_NODES * T_WIN;
#pragma unroll
    for (int r = 0; r < 8; r++) {
        int row = t + 256 * r;
        const float* xr = xb + row * T_WIN;
        float x0 = xr[0], x1 = xr[1], x2 = xr[2], x3 = xr[3], x4 = xr[4];
        float h0 = wb4[0] + x0 * wc[0][0] + x1 * wc[0][1] + x2 * wc[0][2] + x3 * wc[0][3] + x4 * wc[0][4];
        float h1 = wb4[1] + x0 * wc[1][0] + x1 * wc[1][1] + x2 * wc[1][2] + x3 * wc[1][3] + x4 * wc[1][4];
        float h2 = wb4[2] + x0 * wc[2][0] + x1 * wc[2][1] + x2 * wc[2][2] + x3 * wc[2][3] + x4 * wc[2][4];
        float h3 = wb4[3] + x0 * wc[3][0] + x1 * wc[3][1] + x2 * wc[3][2] + x3 * wc[3][3] + x4 * wc[3][4];
        *(float2*)&hts[row][0] = make_float2(h0, h1);
        *(float2*)&hts[row][2] = make_float2(h2, h3);
    }
    __syncthreads();

    // ---- gather: 2048 items, 8 per thread ----
    float sacc[4] = {0.f, 0.f, 0.f, 0.f};
    float sacc2[4] = {0.f, 0.f, 0.f, 0.f};
    const float2* pb = paT + (size_t)b * TOPK * N_NODES;
#pragma unroll 1
    for (int r = 0; r < 8; r++) {
        int i = 256 * r + t;
        float4 z = make_float4(0.f, 0.f, 0.f, 0.f);
#pragma unroll
        for (int k = 0; k < TOPK; k++) {
            float2 pa = pb[(size_t)k * N_NODES + i];   // coalesced b64
            int jk = __float_as_int(pa.y);
            float a = pa.x;
            float2 h01 = *(const float2*)&hts[jk][0];
            float2 h23 = *(const float2*)&hts[jk][2];
            z.x = fmaf(a, h01.x, z.x);
            z.y = fmaf(a, h01.y, z.y);
            z.z = fmaf(a, h23.x, z.z);
            z.w = fmaf(a, h23.y, z.w);
        }
        float4 e4 = *(const float4*)(emb + (size_t)i * D_EMB + d0);
        float4 o;
        o.x = fmaxf(z.x, 0.f) * e4.x;
        o.y = fmaxf(z.y, 0.f) * e4.y;
        o.z = fmaxf(z.z, 0.f) * e4.z;
        o.w = fmaxf(z.w, 0.f) * e4.w;
        ((float4*)obufT)[((size_t)c * B_BATCH + b) * N_NODES + i] = o;
        sacc[0] += o.x; sacc[1] += o.y; sacc[2] += o.z; sacc[3] += o.w;
        sacc2[0] += o.x * o.x; sacc2[1] += o.y * o.y;
        sacc2[2] += o.z * o.z; sacc2[3] += o.w * o.w;
    }

    // ---- stats partials ----
#pragma unroll
    for (int q = 0; q < 4; q++) {
        sacc[q] = wave_sum(sacc[q]);
        sacc2[q] = wave_sum(sacc2[q]);
    }
    if (lane == 0) {
#pragma unroll
        for (int q = 0; q < 4; q++) {
            sred[0][wid][q] = sacc[q];
            sred[1][wid][q] = sacc2[q];
        }
    }
    __syncthreads();
    if (t < 8) {
        int q = t & 3, which = t >> 2;
        float v = sred[which][0][q] + sred[which][1][q] + sred[which][2][q] + sred[which][3][q];
        float* dst = which ? stats2 : stats;
        atomicAdd(&dst[(d0 + q) * STATS_STRIDE], v);
    }
}

// ---------------- K5: BN apply + relu + fc — coalesced c-panel sweep --------
__global__ __launch_bounds__(256) void k_out(
    const float* __restrict__ obufT, const float* __restrict__ stats,
    const float* __restrict__ stats2, const float* __restrict__ gamma,
    const float* __restrict__ beta, const float* __restrict__ fc_w,
    const float* __restrict__ fc_b, float* __restrict__ out) {
    __shared__ float smean[64], sinv[64], sg[64], sb[64], sf[64];
    int t = threadIdx.x;
    int g = blockIdx.x;                 // 256 = 32 b x 8 n-chunks
    int b = g & 31, nc = g >> 5;
    int n = nc * 256 + t;
    const float invM = 1.0f / (float)BN_TOTAL;

    if (t < 64) {
        float mn = stats[t * STATS_STRIDE] * invM;
        float var = stats2[t * STATS_STRIDE] * invM - mn * mn;
        smean[t] = mn;
        sinv[t] = rsqrtf(var + EPS_BN);
        sg[t] = gamma[t]; sb[t] = beta[t]; sf[t] = fc_w[t];
    }
    __syncthreads();

    float fb = fc_b[0];
    float p = 0.f;
#pragma unroll
    for (int c = 0; c < 16; c++) {
        float4 o = ((const float4*)obufT)[((size_t)c * B_BATCH + b) * N_NODES + n];
        int d = 4 * c;
        float v;
        v = fmaxf((o.x - smean[d + 0]) * sinv[d + 0] * sg[d + 0] + sb[d + 0], 0.f); p = fmaf(v, sf[d + 0], p);
        v = fmaxf((o.y - smean[d + 1]) * sinv[d + 1] * sg[d + 1] + sb[d + 1], 0.f); p = fmaf(v, sf[d + 1], p);
        v = fmaxf((o.z - smean[d + 2]) * sinv[d + 2] * sg[d + 2] + sb[d + 2], 0.f); p = fmaf(v, sf[d + 2], p);
        v = fmaxf((o.w - smean[d + 3]) * sinv[d + 3] * sg[d + 3] + sb[d + 3], 0.f); p = fmaf(v, sf[d + 3], p);
    }
    out[b * N_NODES + n] = p + fb;
}

// ---------------- launch ----------------------------------------------------
extern "C" void kernel_launch(void* const* d_in, const int* in_sizes, int n_in,
                              void* d_out, int out_size, void* d_ws, size_t ws_size,
                              hipStream_t stream) {
    const float* x     = (const float*)d_in[0];
    const float* emb   = (const float*)d_in[1];
    const float* W     = (const float*)d_in[2];
    const float* Wb    = (const float*)d_in[3];
    const float* a_src = (const float*)d_in[4];
    const float* a_dst = (const float*)d_in[5];
    const float* gamma = (const float*)d_in[6];
    const float* beta  = (const float*)d_in[7];
    const float* fc_w  = (const float*)d_in[8];
    const float* fc_b  = (const float*)d_in[9];
    float* out = (float*)d_out;

    char* ws = (char*)d_ws;
    float*  stats  = (float*) (ws + 0);            // 4 KB
    float*  stats2 = (float*) (ws + 4096);         // 4 KB
    int*    idxT   = (int*)   (ws + 8192);         // 172032 B
    float*  norms  = (float*) (ws + 180224);       // 8 KB
    float*  es2T   = (float*) (ws + 188416);       // 256 KB [b][n]
    float*  ed2T   = (float*) (ws + 450560);       // 256 KB [b][n]
    float2* paT    = (float2*)(ws + 712704);       // 11010048 B [b][k][i] packed
    float*  cosM   = (float*) (ws + 11722752);     // 16 MB — aliased with obufT
    float*  obufT  = cosM;                         // (cosM dead after k_select)
    // total: 28,499,968 bytes

    k_edge<<<2048, 256, 0, stream>>>(x, W, Wb, a_src, a_dst, emb,
                                     es2T, ed2T, norms, stats, stats2);
    k_gram<<<528, 256, 0, stream>>>(emb, norms, cosM);
    k_select<<<N_NODES / 4, 256, 0, stream>>>(cosM, idxT);
    k_alpha<<<256, 256, 0, stream>>>(idxT, es2T, ed2T, paT);
    k_msg<<<512, 256, 0, stream>>>(x, W, Wb, paT, emb, obufT, stats, stats2);
    k_out<<<256, 256, 0, stream>>>(obufT, stats, stats2, gamma, beta, fc_w, fc_b, out);
}

// Round 5
// 145.635 us; speedup vs baseline: 1.1740x; 1.0214x over previous
//
#include <hip/hip_runtime.h>
#include <math.h>

#define N_NODES 2048
#define T_WIN 5
#define D_EMB 64
#define TOPK 21
#define B_BATCH 32
#define BN_TOTAL (B_BATCH * N_NODES)   // 65536
#define EPS_BN 1e-5f
#define NEG_SLOPE 0.2f
#define STATS_STRIDE 16

typedef unsigned long long u64;

// ---------------- wave-level helpers (wave = 64 on gfx950) ----------------
__device__ __forceinline__ float wave_sum(float v) {
#pragma unroll
    for (int off = 32; off > 0; off >>= 1) v += __shfl_xor(v, off, 64);
    return v;
}

__device__ __forceinline__ u64 max64(u64 a, u64 b) { return a > b ? a : b; }
__device__ __forceinline__ u64 min64(u64 a, u64 b) { return a < b ? a : b; }

__device__ __forceinline__ u64 bitonic_sort64_desc(u64 key, int lane) {
#pragma unroll
    for (int k = 2; k <= 64; k <<= 1) {
#pragma unroll
        for (int j = k >> 1; j >= 1; j >>= 1) {
            u64 pk = __shfl_xor(key, j, 64);
            bool dirDesc = ((lane & k) == 0);
            bool keepMax = (((lane & j) == 0) == dirDesc);
            key = keepMax ? max64(key, pk) : min64(key, pk);
        }
    }
    return key;
}

__device__ __forceinline__ u64 bitonic_merge_top64(u64 a, u64 b, int lane) {
    u64 br = __shfl(b, 63 - lane, 64);
    u64 c = max64(a, br);
#pragma unroll
    for (int j = 32; j >= 1; j >>= 1) {
        u64 pk = __shfl_xor(c, j, 64);
        bool keepMax = ((lane & j) == 0);
        c = keepMax ? max64(c, pk) : min64(c, pk);
    }
    return c;
}

// ---------------- K1: k_edge — es2T/ed2T [b][n] + norms + stats zero --------
// [R3 post-mortem: grid shape is sacred on this latency-bound serial-shfl
// kernel: 2048 blocks, 8 items/wave. Do not fuse/reshape.]
__global__ __launch_bounds__(256) void k_edge(
    const float* __restrict__ x, const float* __restrict__ W,
    const float* __restrict__ Wb, const float* __restrict__ a_src,
    const float* __restrict__ a_dst, const float* __restrict__ emb,
    float* __restrict__ es2T, float* __restrict__ ed2T,
    float* __restrict__ norms, float* __restrict__ stats,
    float* __restrict__ stats2) {
    if (blockIdx.x < 2) {
        float* p = blockIdx.x ? stats2 : stats;
        ((float4*)p)[threadIdx.x] = make_float4(0.f, 0.f, 0.f, 0.f);
    }
    int wid = threadIdx.x >> 6, lane = threadIdx.x & 63;
    int gw = blockIdx.x * 4 + wid;
    const float* wp = W + lane * T_WIN;
    float w0 = wp[0], w1 = wp[1], w2 = wp[2], w3 = wp[3], w4 = wp[4];
    float bias = Wb[lane];
    float as = a_src[lane], asE = a_src[D_EMB + lane];
    float ad = a_dst[lane], adE = a_dst[D_EMB + lane];

    for (int node = gw; node < BN_TOTAL; node += 8192) {
        int n = node & (N_NODES - 1);
        const float* xp = x + (size_t)node * T_WIN;
        float hv = bias + xp[0] * w0 + xp[1] * w1 + xp[2] * w2 + xp[3] * w3 + xp[4] * w4;
        float e = emb[n * D_EMB + lane];
        if (node < N_NODES) {                   // b==0 pass: also emit norms
            float s2 = wave_sum(e * e);
            if (lane == 0) norms[node] = sqrtf(s2);
        }
        float es = wave_sum(hv * as + e * asE);
        float ed = wave_sum(hv * ad + e * adE);
        if (lane == 0) {
            es2T[node] = es;   // node = b*N + n  -> [b][n] layout
            ed2T[node] = ed;
        }
    }
}

// ---------------- K2a: Gram/cos — upper-triangle blocks, symmetric write ----
__global__ __launch_bounds__(256) void k_gram(
    const float* __restrict__ emb, const float* __restrict__ norms,
    float* __restrict__ cosM) {
    __shared__ __align__(16) float As[64][68];   // [d][i]
    __shared__ __align__(16) float Bs[64][68];   // [d][j]
    int t = threadIdx.x;
    int g = blockIdx.x;                          // 0..527
    int a = (int)((sqrtf(8.f * g + 1.f) - 1.f) * 0.5f);
    while ((a + 1) * (a + 2) / 2 <= g) a++;
    while (a * (a + 1) / 2 > g) a--;
    int bq = g - a * (a + 1) / 2;                // 0..a
    int i0 = a * 64, j0 = bq * 64;

    {
        int r = t >> 2, c0 = t & 3;
        const float4* srcA = (const float4*)(emb + (size_t)(i0 + r) * D_EMB);
        const float4* srcB = (const float4*)(emb + (size_t)(j0 + r) * D_EMB);
#pragma unroll
        for (int k = 0; k < 4; k++) {
            int f4 = c0 + 4 * k;
            float4 v = srcA[f4];
            int d = 4 * f4;
            As[d][r] = v.x; As[d + 1][r] = v.y; As[d + 2][r] = v.z; As[d + 3][r] = v.w;
            float4 w = srcB[f4];
            Bs[d][r] = w.x; Bs[d + 1][r] = w.y; Bs[d + 2][r] = w.z; Bs[d + 3][r] = w.w;
        }
    }
    __syncthreads();

    int ti = t & 15, tj = t >> 4;
    float acc[4][4] = {};
#pragma unroll
    for (int d = 0; d < 64; d++) {
        float4 av = *(const float4*)&As[d][4 * ti];
        float4 bv = *(const float4*)&Bs[d][4 * tj];
        acc[0][0] += av.x * bv.x; acc[0][1] += av.x * bv.y; acc[0][2] += av.x * bv.z; acc[0][3] += av.x * bv.w;
        acc[1][0] += av.y * bv.x; acc[1][1] += av.y * bv.y; acc[1][2] += av.y * bv.z; acc[1][3] += av.y * bv.w;
        acc[2][0] += av.z * bv.x; acc[2][1] += av.z * bv.y; acc[2][2] += av.z * bv.z; acc[2][3] += av.z * bv.w;
        acc[3][0] += av.w * bv.x; acc[3][1] += av.w * bv.y; acc[3][2] += av.w * bv.z; acc[3][3] += av.w * bv.w;
    }

    float nis[4] = {norms[i0 + 4 * ti], norms[i0 + 4 * ti + 1],
                    norms[i0 + 4 * ti + 2], norms[i0 + 4 * ti + 3]};
    float njs[4] = {norms[j0 + 4 * tj], norms[j0 + 4 * tj + 1],
                    norms[j0 + 4 * tj + 2], norms[j0 + 4 * tj + 3]};
#pragma unroll
    for (int r = 0; r < 4; r++) {
        float4 o;
        o.x = acc[r][0] / (nis[r] * njs[0]);
        o.y = acc[r][1] / (nis[r] * njs[1]);
        o.z = acc[r][2] / (nis[r] * njs[2]);
        o.w = acc[r][3] / (nis[r] * njs[3]);
        int i = i0 + 4 * ti + r;
        *(float4*)(cosM + (size_t)i * N_NODES + j0 + 4 * tj) = o;
        cosM[(size_t)(j0 + 4 * tj + 0) * N_NODES + i] = o.x;
        cosM[(size_t)(j0 + 4 * tj + 1) * N_NODES + i] = o.y;
        cosM[(size_t)(j0 + 4 * tj + 2) * N_NODES + i] = o.z;
        cosM[(size_t)(j0 + 4 * tj + 3) * N_NODES + i] = o.w;
    }
}

// ---------------- K2b: top-21 selection — wave-pair split rows --------------
// NEW (r5): each row scanned by a PAIR of waves (1024 entries each, own
// top-64 state + flushes), merged at the end by one LDS exchange +
// bitonic_merge_top64. Identical selection: merged top-64 of two half-top-64s
// contains the exact top-21 (same keys, same ~j tie-break). Grid 1024x4 waves
// -> 4 waves/SIMD (2x TLP of old) and the serial ballot/shfl chain halves.
__global__ __launch_bounds__(256) void k_select(
    const float* __restrict__ cosM, int* __restrict__ idxT) {
    __shared__ u64 candbuf[4][128];
    __shared__ u64 mbuf[2][64];
    int tid = threadIdx.x;
    int wid = tid >> 6, lane = tid & 63;
    int pair = wid >> 1;                 // row within block (0..1)
    int half = wid & 1;                  // 0: j<1024, 1: j>=1024
    int i = blockIdx.x * 2 + pair;
    int jbase = half * (N_NODES / 2);
    const float* row = cosM + (size_t)i * N_NODES + jbase;
    u64* buf = candbuf[wid];

    u64 a = 0;
    u64 t = 0;
    int cnt = 0;
    float vcur = row[lane];

#pragma unroll 1
    for (int c = 0; c < N_NODES / 128; c++) {   // 16 chunks of 64
        int j = c * 64 + lane;
        float v = vcur;
        if (c < N_NODES / 128 - 1) vcur = row[j + 64];
        unsigned u = __float_as_uint(v);
        u = (u & 0x80000000u) ? ~u : (u | 0x80000000u);
        u64 key = ((u64)u << 32) | (unsigned)(~(j + jbase));
        unsigned long long ball = __ballot(key > t);
        if (ball) {
            int ofs = __popcll(ball & ((1ull << lane) - 1ull));
            if (key > t) buf[cnt + ofs] = key;
            cnt += (int)__popcll(ball);
            if (cnt >= 64) {
                u64 nk = buf[lane];
                nk = bitonic_sort64_desc(nk, lane);
                a = bitonic_merge_top64(a, nk, lane);
                t = __shfl(a, 20, 64);
                int rem = cnt - 64;
                u64 mv = (lane < rem) ? buf[64 + lane] : 0;
                if (lane < rem) buf[lane] = mv;
                cnt = rem;
            }
        }
    }
    while (cnt > 0) {
        int take = cnt < 64 ? cnt : 64;
        u64 nk = (lane < take) ? buf[lane] : 0;
        nk = bitonic_sort64_desc(nk, lane);
        a = bitonic_merge_top64(a, nk, lane);
        t = __shfl(a, 20, 64);
        int rem = cnt - take;
        u64 mv = (lane < rem) ? buf[take + lane] : 0;
        if (lane < rem) buf[lane] = mv;
        cnt = rem;
    }

    // pair merge: upper wave publishes its sorted top-64; lower wave merges
    if (half) mbuf[pair][lane] = a;
    __syncthreads();
    if (!half) {
        u64 bv = mbuf[pair][lane];
        a = bitonic_merge_top64(a, bv, lane);
        if (lane < TOPK) idxT[lane * N_NODES + i] = (int)(~(unsigned)a);
    }
}

// ---------------- K3: k_alpha — per-item softmax -> alphaT[b][k][i] ---------
// [R4 post-mortem: float2 {alpha,idx} packing doubled the alpha-stream bytes
// (11 MB vs 5.5+0.17) and was net +1.3 us. Separate streams restored.]
__global__ __launch_bounds__(256) void k_alpha(
    const int* __restrict__ idxT, const float* __restrict__ es2T,
    const float* __restrict__ ed2T, float* __restrict__ alphaT) {
    __shared__ float sed[N_NODES];   // 8 KB
    int g = blockIdx.x;
    int b = g & 31;
    int i0 = (g >> 5) * 256;
    int t = threadIdx.x;

    {
        const float4* src = (const float4*)(ed2T + (size_t)b * N_NODES);
        float4* dst = (float4*)sed;
#pragma unroll
        for (int q = 0; q < 2; q++) dst[t + 256 * q] = src[t + 256 * q];
    }
    __syncthreads();

    int i = i0 + t;
    float es = es2T[(size_t)b * N_NODES + i];
    float ev[TOPK];
    float m = -3e38f;
#pragma unroll
    for (int k = 0; k < TOPK; k++) {
        int jk = idxT[k * N_NODES + i];
        float e = es + sed[jk];
        e = e > 0.f ? e : NEG_SLOPE * e;
        ev[k] = e;
        m = fmaxf(m, e);
    }
    float s = 0.f;
#pragma unroll
    for (int k = 0; k < TOPK; k++) {
        ev[k] = __expf(ev[k] - m);
        s += ev[k];
    }
    float inv = 1.0f / s;
#pragma unroll
    for (int k = 0; k < TOPK; k++)
        alphaT[((size_t)b * TOPK + k) * N_NODES + i] = ev[k] * inv;
}

// ---------------- K4: message passing — LDS h-tile, conflict-padded ---------
// Block = (b, d-chunk of 4). h-tile h[b][:,4c..4c+3] built from x in-LDS.
// [R1 post-mortem: k_msg is LDS/VMEM-issue-throughput bound; keep the alphaT
// round-trip, keep per-neighbor work minimal.]
__global__ __launch_bounds__(256, 2) void k_msg(
    const float* __restrict__ x, const float* __restrict__ W,
    const float* __restrict__ Wb, const int* __restrict__ idxT,
    const float* __restrict__ alphaT, const float* __restrict__ emb,
    float* __restrict__ obufT, float* __restrict__ stats,
    float* __restrict__ stats2) {
    __shared__ float hts[N_NODES][6];          // 48 KB, stride 24 B
    __shared__ float sred[2][4][4];

    int g = blockIdx.x;                        // 512 = 32 b x 16 c
    int b = (g & 7) + 8 * ((g >> 3) & 3);      // XCD-local batches
    int c = g >> 5;
    int d0 = c * 4;
    int t = threadIdx.x;
    int wid = t >> 6, lane = t & 63;

    // ---- build h-tile from x ----
    float wc[4][T_WIN], wb4[4];
#pragma unroll
    for (int q = 0; q < 4; q++) {
        wb4[q] = Wb[d0 + q];
#pragma unroll
        for (int tt = 0; tt < T_WIN; tt++) wc[q][tt] = W[(d0 + q) * T_WIN + tt];
    }
    const float* xb = x + (size_t)b * N_NODES * T_WIN;
#pragma unroll
    for (int r = 0; r < 8; r++) {
        int row = t + 256 * r;
        const float* xr = xb + row * T_WIN;
        float x0 = xr[0], x1 = xr[1], x2 = xr[2], x3 = xr[3], x4 = xr[4];
        float h0 = wb4[0] + x0 * wc[0][0] + x1 * wc[0][1] + x2 * wc[0][2] + x3 * wc[0][3] + x4 * wc[0][4];
        float h1 = wb4[1] + x0 * wc[1][0] + x1 * wc[1][1] + x2 * wc[1][2] + x3 * wc[1][3] + x4 * wc[1][4];
        float h2 = wb4[2] + x0 * wc[2][0] + x1 * wc[2][1] + x2 * wc[2][2] + x3 * wc[2][3] + x4 * wc[2][4];
        float h3 = wb4[3] + x0 * wc[3][0] + x1 * wc[3][1] + x2 * wc[3][2] + x3 * wc[3][3] + x4 * wc[3][4];
        *(float2*)&hts[row][0] = make_float2(h0, h1);
        *(float2*)&hts[row][2] = make_float2(h2, h3);
    }
    __syncthreads();

    // ---- gather: 2048 items, 8 per thread ----
    float sacc[4] = {0.f, 0.f, 0.f, 0.f};
    float sacc2[4] = {0.f, 0.f, 0.f, 0.f};
    const float* aT = alphaT + (size_t)b * TOPK * N_NODES;
#pragma unroll 1
    for (int r = 0; r < 8; r++) {
        int i = 256 * r + t;
        float4 z = make_float4(0.f, 0.f, 0.f, 0.f);
#pragma unroll
        for (int k = 0; k < TOPK; k++) {
            int jk = idxT[k * N_NODES + i];          // coalesced, L2-resident
            float a = aT[(size_t)k * N_NODES + i];   // coalesced
            float2 h01 = *(const float2*)&hts[jk][0];
            float2 h23 = *(const float2*)&hts[jk][2];
            z.x = fmaf(a, h01.x, z.x);
            z.y = fmaf(a, h01.y, z.y);
            z.z = fmaf(a, h23.x, z.z);
            z.w = fmaf(a, h23.y, z.w);
        }
        float4 e4 = *(const float4*)(emb + (size_t)i * D_EMB + d0);
        float4 o;
        o.x = fmaxf(z.x, 0.f) * e4.x;
        o.y = fmaxf(z.y, 0.f) * e4.y;
        o.z = fmaxf(z.z, 0.f) * e4.z;
        o.w = fmaxf(z.w, 0.f) * e4.w;
        ((float4*)obufT)[((size_t)c * B_BATCH + b) * N_NODES + i] = o;
        sacc[0] += o.x; sacc[1] += o.y; sacc[2] += o.z; sacc[3] += o.w;
        sacc2[0] += o.x * o.x; sacc2[1] += o.y * o.y;
        sacc2[2] += o.z * o.z; sacc2[3] += o.w * o.w;
    }

    // ---- stats partials ----
#pragma unroll
    for (int q = 0; q < 4; q++) {
        sacc[q] = wave_sum(sacc[q]);
        sacc2[q] = wave_sum(sacc2[q]);
    }
    if (lane == 0) {
#pragma unroll
        for (int q = 0; q < 4; q++) {
            sred[0][wid][q] = sacc[q];
            sred[1][wid][q] = sacc2[q];
        }
    }
    __syncthreads();
    if (t < 8) {
        int q = t & 3, which = t >> 2;
        float v = sred[which][0][q] + sred[which][1][q] + sred[which][2][q] + sred[which][3][q];
        float* dst = which ? stats2 : stats;
        atomicAdd(&dst[(d0 + q) * STATS_STRIDE], v);
    }
}

// ---------------- K5: BN apply + relu + fc — coalesced c-panel sweep --------
__global__ __launch_bounds__(256) void k_out(
    const float* __restrict__ obufT, const float* __restrict__ stats,
    const float* __restrict__ stats2, const float* __restrict__ gamma,
    const float* __restrict__ beta, const float* __restrict__ fc_w,
    const float* __restrict__ fc_b, float* __restrict__ out) {
    __shared__ float smean[64], sinv[64], sg[64], sb[64], sf[64];
    int t = threadIdx.x;
    int g = blockIdx.x;                 // 256 = 32 b x 8 n-chunks
    int b = g & 31, nc = g >> 5;
    int n = nc * 256 + t;
    const float invM = 1.0f / (float)BN_TOTAL;

    if (t < 64) {
        float mn = stats[t * STATS_STRIDE] * invM;
        float var = stats2[t * STATS_STRIDE] * invM - mn * mn;
        smean[t] = mn;
        sinv[t] = rsqrtf(var + EPS_BN);
        sg[t] = gamma[t]; sb[t] = beta[t]; sf[t] = fc_w[t];
    }
    __syncthreads();

    float fb = fc_b[0];
    float p = 0.f;
#pragma unroll
    for (int c = 0; c < 16; c++) {
        float4 o = ((const float4*)obufT)[((size_t)c * B_BATCH + b) * N_NODES + n];
        int d = 4 * c;
        float v;
        v = fmaxf((o.x - smean[d + 0]) * sinv[d + 0] * sg[d + 0] + sb[d + 0], 0.f); p = fmaf(v, sf[d + 0], p);
        v = fmaxf((o.y - smean[d + 1]) * sinv[d + 1] * sg[d + 1] + sb[d + 1], 0.f); p = fmaf(v, sf[d + 1], p);
        v = fmaxf((o.z - smean[d + 2]) * sinv[d + 2] * sg[d + 2] + sb[d + 2], 0.f); p = fmaf(v, sf[d + 2], p);
        v = fmaxf((o.w - smean[d + 3]) * sinv[d + 3] * sg[d + 3] + sb[d + 3], 0.f); p = fmaf(v, sf[d + 3], p);
    }
    out[b * N_NODES + n] = p + fb;
}

// ---------------- launch ----------------------------------------------------
extern "C" void kernel_launch(void* const* d_in, const int* in_sizes, int n_in,
                              void* d_out, int out_size, void* d_ws, size_t ws_size,
                              hipStream_t stream) {
    const float* x     = (const float*)d_in[0];
    const float* emb   = (const float*)d_in[1];
    const float* W     = (const float*)d_in[2];
    const float* Wb    = (const float*)d_in[3];
    const float* a_src = (const float*)d_in[4];
    const float* a_dst = (const float*)d_in[5];
    const float* gamma = (const float*)d_in[6];
    const float* beta  = (const float*)d_in[7];
    const float* fc_w  = (const float*)d_in[8];
    const float* fc_b  = (const float*)d_in[9];
    float* out = (float*)d_out;

    char* ws = (char*)d_ws;
    float* stats  = (float*)(ws + 0);             // 4 KB
    float* stats2 = (float*)(ws + 4096);          // 4 KB
    int*   idxT   = (int*)  (ws + 8192);          // 172032 B
    float* norms  = (float*)(ws + 180224);        // 8 KB
    float* es2T   = (float*)(ws + 188416);        // 256 KB [b][n]
    float* ed2T   = (float*)(ws + 450560);        // 256 KB [b][n]
    float* alphaT = (float*)(ws + 712704);        // 5505024 B [b][k][i]
    float* cosM   = (float*)(ws + 6217728);       // 16 MB — aliased with obufT
    float* obufT  = cosM;                         // (cosM dead after k_select)
    // total: 22,994,944 bytes

    k_edge<<<2048, 256, 0, stream>>>(x, W, Wb, a_src, a_dst, emb,
                                     es2T, ed2T, norms, stats, stats2);
    k_gram<<<528, 256, 0, stream>>>(emb, norms, cosM);
    k_select<<<N_NODES / 2, 256, 0, stream>>>(cosM, idxT);
    k_alpha<<<256, 256, 0, stream>>>(idxT, es2T, ed2T, alphaT);
    k_msg<<<512, 256, 0, stream>>>(x, W, Wb, idxT, alphaT, emb, obufT, stats, stats2);
    k_out<<<256, 256, 0, stream>>>(obufT, stats, stats2, gamma, beta, fc_w, fc_b, out);
}

// Round 6
// 137.114 us; speedup vs baseline: 1.2469x; 1.0621x over previous
//
#include <hip/hip_runtime.h>
#include <math.h>

#define N_NODES 2048
#define T_WIN 5
#define D_EMB 64
#define TOPK 21
#define B_BATCH 32
#define BN_TOTAL (B_BATCH * N_NODES)   // 65536
#define EPS_BN 1e-5f
#define NEG_SLOPE 0.2f
#define STATS_STRIDE 16

typedef unsigned long long u64;

// ---------------- wave-level helpers (wave = 64 on gfx950) ----------------
__device__ __forceinline__ float wave_sum(float v) {
#pragma unroll
    for (int off = 32; off > 0; off >>= 1) v += __shfl_xor(v, off, 64);
    return v;
}

__device__ __forceinline__ u64 max64(u64 a, u64 b) { return a > b ? a : b; }
__device__ __forceinline__ u64 min64(u64 a, u64 b) { return a < b ? a : b; }

__device__ __forceinline__ u64 bitonic_sort64_desc(u64 key, int lane) {
#pragma unroll
    for (int k = 2; k <= 64; k <<= 1) {
#pragma unroll
        for (int j = k >> 1; j >= 1; j >>= 1) {
            u64 pk = __shfl_xor(key, j, 64);
            bool dirDesc = ((lane & k) == 0);
            bool keepMax = (((lane & j) == 0) == dirDesc);
            key = keepMax ? max64(key, pk) : min64(key, pk);
        }
    }
    return key;
}

__device__ __forceinline__ u64 bitonic_merge_top64(u64 a, u64 b, int lane) {
    u64 br = __shfl(b, 63 - lane, 64);
    u64 c = max64(a, br);
#pragma unroll
    for (int j = 32; j >= 1; j >>= 1) {
        u64 pk = __shfl_xor(c, j, 64);
        bool keepMax = ((lane & j) == 0);
        c = keepMax ? max64(c, pk) : min64(c, pk);
    }
    return c;
}

// ---------------- K1: k_pre — algebraic edge collapse + node precompute -----
// NEW (r6): es[b,n] = Sum_d hv_d*as_d + Sum_d e_d*asE_d collapses:
//   h-half  = bs + Sum_t x[b,n,t]*ws_t   (ws_t = Sum_d W[d,t]*as_d, 5 FMAs)
//   emb-half= es_emb[n]                   (batch-independent, 2048 dots only)
// Old k_edge burned 3 serial 18-shfl wave_sums per 65536 items; new kernel
// does 3 wave_sums per 2048 nodes + a 5-FMA stream over 65536 items.
// Exact algebra (fp reassociation only); top-k path (norms/emb) untouched.
// Blocks 0..511: node path (wave per node). Blocks 512..575: x-dot path.
__global__ __launch_bounds__(256) void k_pre(
    const float* __restrict__ x, const float* __restrict__ W,
    const float* __restrict__ Wb, const float* __restrict__ a_src,
    const float* __restrict__ a_dst, const float* __restrict__ emb,
    float* __restrict__ xs2T, float* __restrict__ xd2T,
    float* __restrict__ es_embP, float* __restrict__ ed_embP,
    float* __restrict__ norms, float* __restrict__ stats,
    float* __restrict__ stats2) {
    int t = threadIdx.x;
    if (blockIdx.x < 512) {
        if (blockIdx.x < 2) {
            float* p = blockIdx.x ? stats2 : stats;
            ((float4*)p)[t] = make_float4(0.f, 0.f, 0.f, 0.f);
        }
        int wid = t >> 6, lane = t & 63;
        int node = blockIdx.x * 4 + wid;
        float e = emb[node * D_EMB + lane];
        float s2 = wave_sum(e * e);
        float esE = wave_sum(e * a_src[D_EMB + lane]);
        float edE = wave_sum(e * a_dst[D_EMB + lane]);
        if (lane == 0) {
            norms[node] = sqrtf(s2);
            es_embP[node] = esE;
            ed_embP[node] = edE;
        }
        return;
    }

    // ---- x path: xs/xd = bs + Sum_t x*w -------------------------------------
    __shared__ float cws[5], cwd[5], cbs[2];
    if (t < 12) {
        int which = (t < 5 || t == 10) ? 0 : 1;       // 0: src, 1: dst
        const float* av = which ? a_dst : a_src;
        const float* sp;
        int stride;
        if (t < 10) { int tt = (t < 5) ? t : t - 5; sp = W + tt; stride = T_WIN; }
        else        { sp = Wb; stride = 1; }
        float acc = 0.f;
        for (int d = 0; d < D_EMB; d++) acc += sp[d * stride] * av[d];
        if (t < 5)       cws[t] = acc;
        else if (t < 10) cwd[t - 5] = acc;
        else             cbs[t - 10] = acc;
    }
    __syncthreads();
    float ws0 = cws[0], ws1 = cws[1], ws2 = cws[2], ws3 = cws[3], ws4 = cws[4];
    float wd0 = cwd[0], wd1 = cwd[1], wd2 = cwd[2], wd3 = cwd[3], wd4 = cwd[4];
    float bss = cbs[0], bsd = cbs[1];

    int base = (blockIdx.x - 512) * 1024;
#pragma unroll
    for (int r = 0; r < 4; r++) {
        int item = base + 256 * r + t;
        const float* xp = x + (size_t)item * T_WIN;
        float x0 = xp[0], x1 = xp[1], x2 = xp[2], x3 = xp[3], x4 = xp[4];
        xs2T[item] = bss + x0 * ws0 + x1 * ws1 + x2 * ws2 + x3 * ws3 + x4 * ws4;
        xd2T[item] = bsd + x0 * wd0 + x1 * wd1 + x2 * wd2 + x3 * wd3 + x4 * wd4;
    }
}

// ---------------- K2a: Gram/cos — upper-triangle blocks, symmetric write ----
__global__ __launch_bounds__(256) void k_gram(
    const float* __restrict__ emb, const float* __restrict__ norms,
    float* __restrict__ cosM) {
    __shared__ __align__(16) float As[64][68];   // [d][i]
    __shared__ __align__(16) float Bs[64][68];   // [d][j]
    int t = threadIdx.x;
    int g = blockIdx.x;                          // 0..527
    int a = (int)((sqrtf(8.f * g + 1.f) - 1.f) * 0.5f);
    while ((a + 1) * (a + 2) / 2 <= g) a++;
    while (a * (a + 1) / 2 > g) a--;
    int bq = g - a * (a + 1) / 2;                // 0..a
    int i0 = a * 64, j0 = bq * 64;

    {
        int r = t >> 2, c0 = t & 3;
        const float4* srcA = (const float4*)(emb + (size_t)(i0 + r) * D_EMB);
        const float4* srcB = (const float4*)(emb + (size_t)(j0 + r) * D_EMB);
#pragma unroll
        for (int k = 0; k < 4; k++) {
            int f4 = c0 + 4 * k;
            float4 v = srcA[f4];
            int d = 4 * f4;
            As[d][r] = v.x; As[d + 1][r] = v.y; As[d + 2][r] = v.z; As[d + 3][r] = v.w;
            float4 w = srcB[f4];
            Bs[d][r] = w.x; Bs[d + 1][r] = w.y; Bs[d + 2][r] = w.z; Bs[d + 3][r] = w.w;
        }
    }
    __syncthreads();

    int ti = t & 15, tj = t >> 4;
    float acc[4][4] = {};
#pragma unroll
    for (int d = 0; d < 64; d++) {
        float4 av = *(const float4*)&As[d][4 * ti];
        float4 bv = *(const float4*)&Bs[d][4 * tj];
        acc[0][0] += av.x * bv.x; acc[0][1] += av.x * bv.y; acc[0][2] += av.x * bv.z; acc[0][3] += av.x * bv.w;
        acc[1][0] += av.y * bv.x; acc[1][1] += av.y * bv.y; acc[1][2] += av.y * bv.z; acc[1][3] += av.y * bv.w;
        acc[2][0] += av.z * bv.x; acc[2][1] += av.z * bv.y; acc[2][2] += av.z * bv.z; acc[2][3] += av.z * bv.w;
        acc[3][0] += av.w * bv.x; acc[3][1] += av.w * bv.y; acc[3][2] += av.w * bv.z; acc[3][3] += av.w * bv.w;
    }

    float nis[4] = {norms[i0 + 4 * ti], norms[i0 + 4 * ti + 1],
                    norms[i0 + 4 * ti + 2], norms[i0 + 4 * ti + 3]};
    float njs[4] = {norms[j0 + 4 * tj], norms[j0 + 4 * tj + 1],
                    norms[j0 + 4 * tj + 2], norms[j0 + 4 * tj + 3]};
#pragma unroll
    for (int r = 0; r < 4; r++) {
        float4 o;
        o.x = acc[r][0] / (nis[r] * njs[0]);
        o.y = acc[r][1] / (nis[r] * njs[1]);
        o.z = acc[r][2] / (nis[r] * njs[2]);
        o.w = acc[r][3] / (nis[r] * njs[3]);
        int i = i0 + 4 * ti + r;
        *(float4*)(cosM + (size_t)i * N_NODES + j0 + 4 * tj) = o;
        cosM[(size_t)(j0 + 4 * tj + 0) * N_NODES + i] = o.x;
        cosM[(size_t)(j0 + 4 * tj + 1) * N_NODES + i] = o.y;
        cosM[(size_t)(j0 + 4 * tj + 2) * N_NODES + i] = o.z;
        cosM[(size_t)(j0 + 4 * tj + 3) * N_NODES + i] = o.w;
    }
}

// ---------------- K2b: top-21 selection — wave-pair split rows --------------
// [R5: pair of waves per row (1024 entries each), LDS merge. 4 waves/SIMD.]
__global__ __launch_bounds__(256) void k_select(
    const float* __restrict__ cosM, int* __restrict__ idxT) {
    __shared__ u64 candbuf[4][128];
    __shared__ u64 mbuf[2][64];
    int tid = threadIdx.x;
    int wid = tid >> 6, lane = tid & 63;
    int pair = wid >> 1;                 // row within block (0..1)
    int half = wid & 1;                  // 0: j<1024, 1: j>=1024
    int i = blockIdx.x * 2 + pair;
    int jbase = half * (N_NODES / 2);
    const float* row = cosM + (size_t)i * N_NODES + jbase;
    u64* buf = candbuf[wid];

    u64 a = 0;
    u64 t = 0;
    int cnt = 0;
    float vcur = row[lane];

#pragma unroll 1
    for (int c = 0; c < N_NODES / 128; c++) {   // 16 chunks of 64
        int j = c * 64 + lane;
        float v = vcur;
        if (c < N_NODES / 128 - 1) vcur = row[j + 64];
        unsigned u = __float_as_uint(v);
        u = (u & 0x80000000u) ? ~u : (u | 0x80000000u);
        u64 key = ((u64)u << 32) | (unsigned)(~(j + jbase));
        unsigned long long ball = __ballot(key > t);
        if (ball) {
            int ofs = __popcll(ball & ((1ull << lane) - 1ull));
            if (key > t) buf[cnt + ofs] = key;
            cnt += (int)__popcll(ball);
            if (cnt >= 64) {
                u64 nk = buf[lane];
                nk = bitonic_sort64_desc(nk, lane);
                a = bitonic_merge_top64(a, nk, lane);
                t = __shfl(a, 20, 64);
                int rem = cnt - 64;
                u64 mv = (lane < rem) ? buf[64 + lane] : 0;
                if (lane < rem) buf[lane] = mv;
                cnt = rem;
            }
        }
    }
    while (cnt > 0) {
        int take = cnt < 64 ? cnt : 64;
        u64 nk = (lane < take) ? buf[lane] : 0;
        nk = bitonic_sort64_desc(nk, lane);
        a = bitonic_merge_top64(a, nk, lane);
        t = __shfl(a, 20, 64);
        int rem = cnt - take;
        u64 mv = (lane < rem) ? buf[take + lane] : 0;
        if (lane < rem) buf[lane] = mv;
        cnt = rem;
    }

    // pair merge: upper wave publishes its sorted top-64; lower wave merges
    if (half) mbuf[pair][lane] = a;
    __syncthreads();
    if (!half) {
        u64 bv = mbuf[pair][lane];
        a = bitonic_merge_top64(a, bv, lane);
        if (lane < TOPK) idxT[lane * N_NODES + i] = (int)(~(unsigned)a);
    }
}

// ---------------- K3: k_alpha — softmax from decomposed es/ed ---------------
// es[b,i] = xs2T[b,i] + es_embP[i]; sed[j] = xd2T[b,j] + ed_embP[j]
// (reconstruction of the exact edge values; added during LDS staging).
__global__ __launch_bounds__(256) void k_alpha(
    const int* __restrict__ idxT, const float* __restrict__ xs2T,
    const float* __restrict__ xd2T, const float* __restrict__ es_embP,
    const float* __restrict__ ed_embP, float* __restrict__ alphaT) {
    __shared__ float sed[N_NODES];   // 8 KB
    int g = blockIdx.x;
    int b = g & 31;
    int i0 = (g >> 5) * 256;
    int t = threadIdx.x;

    {
        const float4* sxd = (const float4*)(xd2T + (size_t)b * N_NODES);
        const float4* sde = (const float4*)(ed_embP);
        float4* dst = (float4*)sed;
#pragma unroll
        for (int q = 0; q < 2; q++) {
            int idx = t + 256 * q;
            float4 u = sxd[idx];
            float4 v = sde[idx];
            dst[idx] = make_float4(u.x + v.x, u.y + v.y, u.z + v.z, u.w + v.w);
        }
    }
    __syncthreads();

    int i = i0 + t;
    float es = xs2T[(size_t)b * N_NODES + i] + es_embP[i];
    float ev[TOPK];
    float m = -3e38f;
#pragma unroll
    for (int k = 0; k < TOPK; k++) {
        int jk = idxT[k * N_NODES + i];
        float e = es + sed[jk];
        e = e > 0.f ? e : NEG_SLOPE * e;
        ev[k] = e;
        m = fmaxf(m, e);
    }
    float s = 0.f;
#pragma unroll
    for (int k = 0; k < TOPK; k++) {
        ev[k] = __expf(ev[k] - m);
        s += ev[k];
    }
    float inv = 1.0f / s;
#pragma unroll
    for (int k = 0; k < TOPK; k++)
        alphaT[((size_t)b * TOPK + k) * N_NODES + i] = ev[k] * inv;
}

// ---------------- K4: message passing — LDS h-tile, conflict-padded ---------
// [R1 post-mortem: LDS/VMEM-issue-throughput bound; keep per-neighbor work
// minimal; alphaT round-trip is cheaper than recompute.]
__global__ __launch_bounds__(256, 2) void k_msg(
    const float* __restrict__ x, const float* __restrict__ W,
    const float* __restrict__ Wb, const int* __restrict__ idxT,
    const float* __restrict__ alphaT, const float* __restrict__ emb,
    float* __restrict__ obufT, float* __restrict__ stats,
    float* __restrict__ stats2) {
    __shared__ float hts[N_NODES][6];          // 48 KB, stride 24 B
    __shared__ float sred[2][4][4];

    int g = blockIdx.x;                        // 512 = 32 b x 16 c
    int b = (g & 7) + 8 * ((g >> 3) & 3);      // XCD-local batches
    int c = g >> 5;
    int d0 = c * 4;
    int t = threadIdx.x;
    int wid = t >> 6, lane = t & 63;

    // ---- build h-tile from x ----
    float wc[4][T_WIN], wb4[4];
#pragma unroll
    for (int q = 0; q < 4; q++) {
        wb4[q] = Wb[d0 + q];
#pragma unroll
        for (int tt = 0; tt < T_WIN; tt++) wc[q][tt] = W[(d0 + q) * T_WIN + tt];
    }
    const float* xb = x + (size_t)b * N_NODES * T_WIN;
#pragma unroll
    for (int r = 0; r < 8; r++) {
        int row = t + 256 * r;
        const float* xr = xb + row * T_WIN;
        float x0 = xr[0], x1 = xr[1], x2 = xr[2], x3 = xr[3], x4 = xr[4];
        float h0 = wb4[0] + x0 * wc[0][0] + x1 * wc[0][1] + x2 * wc[0][2] + x3 * wc[0][3] + x4 * wc[0][4];
        float h1 = wb4[1] + x0 * wc[1][0] + x1 * wc[1][1] + x2 * wc[1][2] + x3 * wc[1][3] + x4 * wc[1][4];
        float h2 = wb4[2] + x0 * wc[2][0] + x1 * wc[2][1] + x2 * wc[2][2] + x3 * wc[2][3] + x4 * wc[2][4];
        float h3 = wb4[3] + x0 * wc[3][0] + x1 * wc[3][1] + x2 * wc[3][2] + x3 * wc[3][3] + x4 * wc[3][4];
        *(float2*)&hts[row][0] = make_float2(h0, h1);
        *(float2*)&hts[row][2] = make_float2(h2, h3);
    }
    __syncthreads();

    // ---- gather: 2048 items, 8 per thread ----
    float sacc[4] = {0.f, 0.f, 0.f, 0.f};
    float sacc2[4] = {0.f, 0.f, 0.f, 0.f};
    const float* aT = alphaT + (size_t)b * TOPK * N_NODES;
#pragma unroll 1
    for (int r = 0; r < 8; r++) {
        int i = 256 * r + t;
        float4 z = make_float4(0.f, 0.f, 0.f, 0.f);
#pragma unroll
        for (int k = 0; k < TOPK; k++) {
            int jk = idxT[k * N_NODES + i];          // coalesced, L2-resident
            float a = aT[(size_t)k * N_NODES + i];   // coalesced
            float2 h01 = *(const float2*)&hts[jk][0];
            float2 h23 = *(const float2*)&hts[jk][2];
            z.x = fmaf(a, h01.x, z.x);
            z.y = fmaf(a, h01.y, z.y);
            z.z = fmaf(a, h23.x, z.z);
            z.w = fmaf(a, h23.y, z.w);
        }
        float4 e4 = *(const float4*)(emb + (size_t)i * D_EMB + d0);
        float4 o;
        o.x = fmaxf(z.x, 0.f) * e4.x;
        o.y = fmaxf(z.y, 0.f) * e4.y;
        o.z = fmaxf(z.z, 0.f) * e4.z;
        o.w = fmaxf(z.w, 0.f) * e4.w;
        ((float4*)obufT)[((size_t)c * B_BATCH + b) * N_NODES + i] = o;
        sacc[0] += o.x; sacc[1] += o.y; sacc[2] += o.z; sacc[3] += o.w;
        sacc2[0] += o.x * o.x; sacc2[1] += o.y * o.y;
        sacc2[2] += o.z * o.z; sacc2[3] += o.w * o.w;
    }

    // ---- stats partials ----
#pragma unroll
    for (int q = 0; q < 4; q++) {
        sacc[q] = wave_sum(sacc[q]);
        sacc2[q] = wave_sum(sacc2[q]);
    }
    if (lane == 0) {
#pragma unroll
        for (int q = 0; q < 4; q++) {
            sred[0][wid][q] = sacc[q];
            sred[1][wid][q] = sacc2[q];
        }
    }
    __syncthreads();
    if (t < 8) {
        int q = t & 3, which = t >> 2;
        float v = sred[which][0][q] + sred[which][1][q] + sred[which][2][q] + sred[which][3][q];
        float* dst = which ? stats2 : stats;
        atomicAdd(&dst[(d0 + q) * STATS_STRIDE], v);
    }
}

// ---------------- K5: BN apply + relu + fc — coalesced c-panel sweep --------
__global__ __launch_bounds__(256) void k_out(
    const float* __restrict__ obufT, const float* __restrict__ stats,
    const float* __restrict__ stats2, const float* __restrict__ gamma,
    const float* __restrict__ beta, const float* __restrict__ fc_w,
    const float* __restrict__ fc_b, float* __restrict__ out) {
    __shared__ float smean[64], sinv[64], sg[64], sb[64], sf[64];
    int t = threadIdx.x;
    int g = blockIdx.x;                 // 256 = 32 b x 8 n-chunks
    int b = g & 31, nc = g >> 5;
    int n = nc * 256 + t;
    const float invM = 1.0f / (float)BN_TOTAL;

    if (t < 64) {
        float mn = stats[t * STATS_STRIDE] * invM;
        float var = stats2[t * STATS_STRIDE] * invM - mn * mn;
        smean[t] = mn;
        sinv[t] = rsqrtf(var + EPS_BN);
        sg[t] = gamma[t]; sb[t] = beta[t]; sf[t] = fc_w[t];
    }
    __syncthreads();

    float fb = fc_b[0];
    float p = 0.f;
#pragma unroll
    for (int c = 0; c < 16; c++) {
        float4 o = ((const float4*)obufT)[((size_t)c * B_BATCH + b) * N_NODES + n];
        int d = 4 * c;
        float v;
        v = fmaxf((o.x - smean[d + 0]) * sinv[d + 0] * sg[d + 0] + sb[d + 0], 0.f); p = fmaf(v, sf[d + 0], p);
        v = fmaxf((o.y - smean[d + 1]) * sinv[d + 1] * sg[d + 1] + sb[d + 1], 0.f); p = fmaf(v, sf[d + 1], p);
        v = fmaxf((o.z - smean[d + 2]) * sinv[d + 2] * sg[d + 2] + sb[d + 2], 0.f); p = fmaf(v, sf[d + 2], p);
        v = fmaxf((o.w - smean[d + 3]) * sinv[d + 3] * sg[d + 3] + sb[d + 3], 0.f); p = fmaf(v, sf[d + 3], p);
    }
    out[b * N_NODES + n] = p + fb;
}

// ---------------- launch ----------------------------------------------------
extern "C" void kernel_launch(void* const* d_in, const int* in_sizes, int n_in,
                              void* d_out, int out_size, void* d_ws, size_t ws_size,
                              hipStream_t stream) {
    const float* x     = (const float*)d_in[0];
    const float* emb   = (const float*)d_in[1];
    const float* W     = (const float*)d_in[2];
    const float* Wb    = (const float*)d_in[3];
    const float* a_src = (const float*)d_in[4];
    const float* a_dst = (const float*)d_in[5];
    const float* gamma = (const float*)d_in[6];
    const float* beta  = (const float*)d_in[7];
    const float* fc_w  = (const float*)d_in[8];
    const float* fc_b  = (const float*)d_in[9];
    float* out = (float*)d_out;

    char* ws = (char*)d_ws;
    float* stats   = (float*)(ws + 0);            // 4 KB
    float* stats2  = (float*)(ws + 4096);         // 4 KB
    int*   idxT    = (int*)  (ws + 8192);         // 172032 B
    float* norms   = (float*)(ws + 180224);       // 8 KB
    float* es_embP = (float*)(ws + 188416);       // 8 KB
    float* ed_embP = (float*)(ws + 196608);       // 8 KB
    float* xs2T    = (float*)(ws + 204800);       // 256 KB [b][n]
    float* xd2T    = (float*)(ws + 466944);       // 256 KB [b][n]
    float* alphaT  = (float*)(ws + 729088);       // 5505024 B [b][k][i]
    float* cosM    = (float*)(ws + 6234112);      // 16 MB — aliased with obufT
    float* obufT   = cosM;                        // (cosM dead after k_select)
    // total: 23,011,328 bytes

    k_pre<<<576, 256, 0, stream>>>(x, W, Wb, a_src, a_dst, emb,
                                   xs2T, xd2T, es_embP, ed_embP, norms,
                                   stats, stats2);
    k_gram<<<528, 256, 0, stream>>>(emb, norms, cosM);
    k_select<<<N_NODES / 2, 256, 0, stream>>>(cosM, idxT);
    k_alpha<<<256, 256, 0, stream>>>(idxT, xs2T, xd2T, es_embP, ed_embP, alphaT);
    k_msg<<<512, 256, 0, stream>>>(x, W, Wb, idxT, alphaT, emb, obufT, stats, stats2);
    k_out<<<256, 256, 0, stream>>>(obufT, stats, stats2, gamma, beta, fc_w, fc_b, out);
}

// Round 7
// 131.447 us; speedup vs baseline: 1.3007x; 1.0431x over previous
//
#include <hip/hip_runtime.h>
#include <math.h>

#define N_NODES 2048
#define T_WIN 5
#define D_EMB 64
#define TOPK 21
#define B_BATCH 32
#define BN_TOTAL (B_BATCH * N_NODES)   // 65536
#define EPS_BN 1e-5f
#define NEG_SLOPE 0.2f
#define STATS_STRIDE 16

typedef unsigned long long u64;

// ---------------- wave-level helpers (wave = 64 on gfx950) ----------------
__device__ __forceinline__ float wave_sum(float v) {
#pragma unroll
    for (int off = 32; off > 0; off >>= 1) v += __shfl_xor(v, off, 64);
    return v;
}

__device__ __forceinline__ u64 max64(u64 a, u64 b) { return a > b ? a : b; }
__device__ __forceinline__ u64 min64(u64 a, u64 b) { return a < b ? a : b; }

__device__ __forceinline__ u64 bitonic_sort64_desc(u64 key, int lane) {
#pragma unroll
    for (int k = 2; k <= 64; k <<= 1) {
#pragma unroll
        for (int j = k >> 1; j >= 1; j >>= 1) {
            u64 pk = __shfl_xor(key, j, 64);
            bool dirDesc = ((lane & k) == 0);
            bool keepMax = (((lane & j) == 0) == dirDesc);
            key = keepMax ? max64(key, pk) : min64(key, pk);
        }
    }
    return key;
}

__device__ __forceinline__ u64 bitonic_merge_top64(u64 a, u64 b, int lane) {
    u64 br = __shfl(b, 63 - lane, 64);
    u64 c = max64(a, br);
#pragma unroll
    for (int j = 32; j >= 1; j >>= 1) {
        u64 pk = __shfl_xor(c, j, 64);
        bool keepMax = ((lane & j) == 0);
        c = keepMax ? max64(c, pk) : min64(c, pk);
    }
    return c;
}

// ---------------- K1: k_preg — fused {raw Gram tiles} + {edge precompute} ---
// Gram path (blocks 0..527) writes RAW dot products; the /(ni*nj) moves to
// k_select with identical operands/order -> bit-identical cos keys (this
// exact decomposition passed in R3 at absmax 0.0039; R3's regression was the
// edge-TLP collapse, not this). Removing gram's norms dependency lets both
// paths share one dispatch. Pre paths keep their exact R6 per-wave shapes:
// node path blocks 528..1039 (wave per node), x path blocks 1040..1103.
__global__ __launch_bounds__(256) void k_preg(
    const float* __restrict__ x, const float* __restrict__ W,
    const float* __restrict__ Wb, const float* __restrict__ a_src,
    const float* __restrict__ a_dst, const float* __restrict__ emb,
    float* __restrict__ xs2T, float* __restrict__ xd2T,
    float* __restrict__ es_embP, float* __restrict__ ed_embP,
    float* __restrict__ norms, float* __restrict__ dotM,
    float* __restrict__ stats, float* __restrict__ stats2) {
    __shared__ __align__(16) float As[64][68];   // [d][i] (gram path only)
    __shared__ __align__(16) float Bs[64][68];   // [d][j]
    int t = threadIdx.x;

    if (blockIdx.x >= 528) {
        int eb = blockIdx.x - 528;
        if (eb < 512) {
            // ---- node path: norms + es_emb/ed_emb (wave per node) ----
            if (eb < 2) {
                float* p = eb ? stats2 : stats;
                ((float4*)p)[t] = make_float4(0.f, 0.f, 0.f, 0.f);
            }
            int wid = t >> 6, lane = t & 63;
            int node = eb * 4 + wid;
            float e = emb[node * D_EMB + lane];
            float s2 = wave_sum(e * e);
            float esE = wave_sum(e * a_src[D_EMB + lane]);
            float edE = wave_sum(e * a_dst[D_EMB + lane]);
            if (lane == 0) {
                norms[node] = sqrtf(s2);
                es_embP[node] = esE;
                ed_embP[node] = edE;
            }
        } else {
            // ---- x path: xs/xd = bs + Sum_t x*w ----
            __shared__ float cws[5], cwd[5], cbs[2];
            if (t < 12) {
                int which = (t < 5 || t == 10) ? 0 : 1;
                const float* av = which ? a_dst : a_src;
                const float* sp;
                int stride;
                if (t < 10) { int tt = (t < 5) ? t : t - 5; sp = W + tt; stride = T_WIN; }
                else        { sp = Wb; stride = 1; }
                float acc = 0.f;
                for (int d = 0; d < D_EMB; d++) acc += sp[d * stride] * av[d];
                if (t < 5)       cws[t] = acc;
                else if (t < 10) cwd[t - 5] = acc;
                else             cbs[t - 10] = acc;
            }
            __syncthreads();
            float ws0 = cws[0], ws1 = cws[1], ws2 = cws[2], ws3 = cws[3], ws4 = cws[4];
            float wd0 = cwd[0], wd1 = cwd[1], wd2 = cwd[2], wd3 = cwd[3], wd4 = cwd[4];
            float bss = cbs[0], bsd = cbs[1];
            int base = (eb - 512) * 1024;
#pragma unroll
            for (int r = 0; r < 4; r++) {
                int item = base + 256 * r + t;
                const float* xp = x + (size_t)item * T_WIN;
                float x0 = xp[0], x1 = xp[1], x2 = xp[2], x3 = xp[3], x4 = xp[4];
                xs2T[item] = bss + x0 * ws0 + x1 * ws1 + x2 * ws2 + x3 * ws3 + x4 * ws4;
                xd2T[item] = bsd + x0 * wd0 + x1 * wd1 + x2 * wd2 + x3 * wd3 + x4 * wd4;
            }
        }
        return;
    }

    // ---- gram path: raw Gram tile, symmetric write (dot exactly symmetric)
    int g = blockIdx.x;                          // 0..527
    int a = (int)((sqrtf(8.f * g + 1.f) - 1.f) * 0.5f);
    while ((a + 1) * (a + 2) / 2 <= g) a++;
    while (a * (a + 1) / 2 > g) a--;
    int bq = g - a * (a + 1) / 2;                // 0..a
    int i0 = a * 64, j0 = bq * 64;

    {
        int r = t >> 2, c0 = t & 3;
        const float4* srcA = (const float4*)(emb + (size_t)(i0 + r) * D_EMB);
        const float4* srcB = (const float4*)(emb + (size_t)(j0 + r) * D_EMB);
#pragma unroll
        for (int k = 0; k < 4; k++) {
            int f4 = c0 + 4 * k;
            float4 v = srcA[f4];
            int d = 4 * f4;
            As[d][r] = v.x; As[d + 1][r] = v.y; As[d + 2][r] = v.z; As[d + 3][r] = v.w;
            float4 w = srcB[f4];
            Bs[d][r] = w.x; Bs[d + 1][r] = w.y; Bs[d + 2][r] = w.z; Bs[d + 3][r] = w.w;
        }
    }
    __syncthreads();

    int ti = t & 15, tj = t >> 4;
    float acc[4][4] = {};
#pragma unroll
    for (int d = 0; d < 64; d++) {
        float4 av = *(const float4*)&As[d][4 * ti];
        float4 bv = *(const float4*)&Bs[d][4 * tj];
        acc[0][0] += av.x * bv.x; acc[0][1] += av.x * bv.y; acc[0][2] += av.x * bv.z; acc[0][3] += av.x * bv.w;
        acc[1][0] += av.y * bv.x; acc[1][1] += av.y * bv.y; acc[1][2] += av.y * bv.z; acc[1][3] += av.y * bv.w;
        acc[2][0] += av.z * bv.x; acc[2][1] += av.z * bv.y; acc[2][2] += av.z * bv.z; acc[2][3] += av.z * bv.w;
        acc[3][0] += av.w * bv.x; acc[3][1] += av.w * bv.y; acc[3][2] += av.w * bv.z; acc[3][3] += av.w * bv.w;
    }

#pragma unroll
    for (int r = 0; r < 4; r++) {
        float4 o;
        o.x = acc[r][0]; o.y = acc[r][1]; o.z = acc[r][2]; o.w = acc[r][3];
        int i = i0 + 4 * ti + r;
        *(float4*)(dotM + (size_t)i * N_NODES + j0 + 4 * tj) = o;
        dotM[(size_t)(j0 + 4 * tj + 0) * N_NODES + i] = o.x;
        dotM[(size_t)(j0 + 4 * tj + 1) * N_NODES + i] = o.y;
        dotM[(size_t)(j0 + 4 * tj + 2) * N_NODES + i] = o.z;
        dotM[(size_t)(j0 + 4 * tj + 3) * N_NODES + i] = o.w;
    }
}

// ---------------- K2: top-21 selection — wave-pair split, on-the-fly norm ---
// v = dot/(ni*nv): identical operands and IEEE ops as the old k_gram divide
// -> key bits identical -> selection identical (R3-verified decomposition).
__global__ __launch_bounds__(256) void k_select(
    const float* __restrict__ dotM, const float* __restrict__ norms,
    int* __restrict__ idxT) {
    __shared__ u64 candbuf[4][128];
    __shared__ u64 mbuf[2][64];
    int tid = threadIdx.x;
    int wid = tid >> 6, lane = tid & 63;
    int pair = wid >> 1;                 // row within block (0..1)
    int half = wid & 1;                  // 0: j<1024, 1: j>=1024
    int i = blockIdx.x * 2 + pair;
    int jbase = half * (N_NODES / 2);
    const float* row = dotM + (size_t)i * N_NODES + jbase;
    u64* buf = candbuf[wid];
    float ni = norms[i];

    u64 a = 0;
    u64 t = 0;
    int cnt = 0;
    float vcur = row[lane];
    float ncur = norms[jbase + lane];

#pragma unroll 1
    for (int c = 0; c < N_NODES / 128; c++) {   // 16 chunks of 64
        int j = c * 64 + lane;
        float dv = vcur, nv = ncur;
        if (c < N_NODES / 128 - 1) {
            vcur = row[j + 64];
            ncur = norms[jbase + j + 64];
        }
        float v = dv / (ni * nv);
        unsigned u = __float_as_uint(v);
        u = (u & 0x80000000u) ? ~u : (u | 0x80000000u);
        u64 key = ((u64)u << 32) | (unsigned)(~(j + jbase));
        unsigned long long ball = __ballot(key > t);
        if (ball) {
            int ofs = __popcll(ball & ((1ull << lane) - 1ull));
            if (key > t) buf[cnt + ofs] = key;
            cnt += (int)__popcll(ball);
            if (cnt >= 64) {
                u64 nk = buf[lane];
                nk = bitonic_sort64_desc(nk, lane);
                a = bitonic_merge_top64(a, nk, lane);
                t = __shfl(a, 20, 64);
                int rem = cnt - 64;
                u64 mv = (lane < rem) ? buf[64 + lane] : 0;
                if (lane < rem) buf[lane] = mv;
                cnt = rem;
            }
        }
    }
    while (cnt > 0) {
        int take = cnt < 64 ? cnt : 64;
        u64 nk = (lane < take) ? buf[lane] : 0;
        nk = bitonic_sort64_desc(nk, lane);
        a = bitonic_merge_top64(a, nk, lane);
        t = __shfl(a, 20, 64);
        int rem = cnt - take;
        u64 mv = (lane < rem) ? buf[take + lane] : 0;
        if (lane < rem) buf[lane] = mv;
        cnt = rem;
    }

    // pair merge: upper wave publishes its sorted top-64; lower wave merges
    if (half) mbuf[pair][lane] = a;
    __syncthreads();
    if (!half) {
        u64 bv = mbuf[pair][lane];
        a = bitonic_merge_top64(a, bv, lane);
        if (lane < TOPK) idxT[lane * N_NODES + i] = (int)(~(unsigned)a);
    }
}

// ---------------- K3: k_alpha — softmax from decomposed es/ed ---------------
__global__ __launch_bounds__(256) void k_alpha(
    const int* __restrict__ idxT, const float* __restrict__ xs2T,
    const float* __restrict__ xd2T, const float* __restrict__ es_embP,
    const float* __restrict__ ed_embP, float* __restrict__ alphaT) {
    __shared__ float sed[N_NODES];   // 8 KB
    int g = blockIdx.x;
    int b = g & 31;
    int i0 = (g >> 5) * 256;
    int t = threadIdx.x;

    {
        const float4* sxd = (const float4*)(xd2T + (size_t)b * N_NODES);
        const float4* sde = (const float4*)(ed_embP);
        float4* dst = (float4*)sed;
#pragma unroll
        for (int q = 0; q < 2; q++) {
            int idx = t + 256 * q;
            float4 u = sxd[idx];
            float4 v = sde[idx];
            dst[idx] = make_float4(u.x + v.x, u.y + v.y, u.z + v.z, u.w + v.w);
        }
    }
    __syncthreads();

    int i = i0 + t;
    float es = xs2T[(size_t)b * N_NODES + i] + es_embP[i];
    float ev[TOPK];
    float m = -3e38f;
#pragma unroll
    for (int k = 0; k < TOPK; k++) {
        int jk = idxT[k * N_NODES + i];
        float e = es + sed[jk];
        e = e > 0.f ? e : NEG_SLOPE * e;
        ev[k] = e;
        m = fmaxf(m, e);
    }
    float s = 0.f;
#pragma unroll
    for (int k = 0; k < TOPK; k++) {
        ev[k] = __expf(ev[k] - m);
        s += ev[k];
    }
    float inv = 1.0f / s;
#pragma unroll
    for (int k = 0; k < TOPK; k++)
        alphaT[((size_t)b * TOPK + k) * N_NODES + i] = ev[k] * inv;
}

// ---------------- K4: message passing — b128 h-tile, 4 blocks/CU ------------
// NEW (r7): hts[2048][4] = 32 KB, 16 B rows -> ONE ds_read_b128 per neighbor
// (was 2x ds_read_b64 off a 24 B-stride tile): LDS gather instrs halve
// (336->168/wave), and b128's 8-words/bank floor = peak LDS BW. 32 KB tile
// also lifts occupancy 2->4 blocks/CU (__launch_bounds__(256,4), 16 waves/CU)
// to hide random-gather bank imbalance + VMEM latency. Values bit-identical
// (same h, same fmaf order). [R1: kernel is LDS-issue bound -> this attacks
// exactly that. R3: grid shape unchanged, 512 blocks.]
__global__ __launch_bounds__(256, 4) void k_msg(
    const float* __restrict__ x, const float* __restrict__ W,
    const float* __restrict__ Wb, const int* __restrict__ idxT,
    const float* __restrict__ alphaT, const float* __restrict__ emb,
    float* __restrict__ obufT, float* __restrict__ stats,
    float* __restrict__ stats2) {
    __shared__ __align__(16) float hts[N_NODES][4];   // 32 KB, b128 rows
    __shared__ float sred[2][4][4];

    int g = blockIdx.x;                        // 512 = 32 b x 16 c
    int b = (g & 7) + 8 * ((g >> 3) & 3);      // XCD-local batches
    int c = g >> 5;
    int d0 = c * 4;
    int t = threadIdx.x;
    int wid = t >> 6, lane = t & 63;

    // ---- build h-tile from x ----
    float wc[4][T_WIN], wb4[4];
#pragma unroll
    for (int q = 0; q < 4; q++) {
        wb4[q] = Wb[d0 + q];
#pragma unroll
        for (int tt = 0; tt < T_WIN; tt++) wc[q][tt] = W[(d0 + q) * T_WIN + tt];
    }
    const float* xb = x + (size_t)b * N_NODES * T_WIN;
#pragma unroll
    for (int r = 0; r < 8; r++) {
        int row = t + 256 * r;
        const float* xr = xb + row * T_WIN;
        float x0 = xr[0], x1 = xr[1], x2 = xr[2], x3 = xr[3], x4 = xr[4];
        float h0 = wb4[0] + x0 * wc[0][0] + x1 * wc[0][1] + x2 * wc[0][2] + x3 * wc[0][3] + x4 * wc[0][4];
        float h1 = wb4[1] + x0 * wc[1][0] + x1 * wc[1][1] + x2 * wc[1][2] + x3 * wc[1][3] + x4 * wc[1][4];
        float h2 = wb4[2] + x0 * wc[2][0] + x1 * wc[2][1] + x2 * wc[2][2] + x3 * wc[2][3] + x4 * wc[2][4];
        float h3 = wb4[3] + x0 * wc[3][0] + x1 * wc[3][1] + x2 * wc[3][2] + x3 * wc[3][3] + x4 * wc[3][4];
        *(float4*)&hts[row][0] = make_float4(h0, h1, h2, h3);
    }
    __syncthreads();

    // ---- gather: 2048 items, 8 per thread ----
    float sacc[4] = {0.f, 0.f, 0.f, 0.f};
    float sacc2[4] = {0.f, 0.f, 0.f, 0.f};
    const float* aT = alphaT + (size_t)b * TOPK * N_NODES;
#pragma unroll 1
    for (int r = 0; r < 8; r++) {
        int i = 256 * r + t;
        float4 z = make_float4(0.f, 0.f, 0.f, 0.f);
#pragma unroll
        for (int k = 0; k < TOPK; k++) {
            int jk = idxT[k * N_NODES + i];          // coalesced, L2-resident
            float a = aT[(size_t)k * N_NODES + i];   // coalesced
            float4 h4 = *(const float4*)&hts[jk][0]; // one ds_read_b128
            z.x = fmaf(a, h4.x, z.x);
            z.y = fmaf(a, h4.y, z.y);
            z.z = fmaf(a, h4.z, z.z);
            z.w = fmaf(a, h4.w, z.w);
        }
        float4 e4 = *(const float4*)(emb + (size_t)i * D_EMB + d0);
        float4 o;
        o.x = fmaxf(z.x, 0.f) * e4.x;
        o.y = fmaxf(z.y, 0.f) * e4.y;
        o.z = fmaxf(z.z, 0.f) * e4.z;
        o.w = fmaxf(z.w, 0.f) * e4.w;
        ((float4*)obufT)[((size_t)c * B_BATCH + b) * N_NODES + i] = o;
        sacc[0] += o.x; sacc[1] += o.y; sacc[2] += o.z; sacc[3] += o.w;
        sacc2[0] += o.x * o.x; sacc2[1] += o.y * o.y;
        sacc2[2] += o.z * o.z; sacc2[3] += o.w * o.w;
    }

    // ---- stats partials ----
#pragma unroll
    for (int q = 0; q < 4; q++) {
        sacc[q] = wave_sum(sacc[q]);
        sacc2[q] = wave_sum(sacc2[q]);
    }
    if (lane == 0) {
#pragma unroll
        for (int q = 0; q < 4; q++) {
            sred[0][wid][q] = sacc[q];
            sred[1][wid][q] = sacc2[q];
        }
    }
    __syncthreads();
    if (t < 8) {
        int q = t & 3, which = t >> 2;
        float v = sred[which][0][q] + sred[which][1][q] + sred[which][2][q] + sred[which][3][q];
        float* dst = which ? stats2 : stats;
        atomicAdd(&dst[(d0 + q) * STATS_STRIDE], v);
    }
}

// ---------------- K5: BN apply + relu + fc — coalesced c-panel sweep --------
__global__ __launch_bounds__(256) void k_out(
    const float* __restrict__ obufT, const float* __restrict__ stats,
    const float* __restrict__ stats2, const float* __restrict__ gamma,
    const float* __restrict__ beta, const float* __restrict__ fc_w,
    const float* __restrict__ fc_b, float* __restrict__ out) {
    __shared__ float smean[64], sinv[64], sg[64], sb[64], sf[64];
    int t = threadIdx.x;
    int g = blockIdx.x;                 // 256 = 32 b x 8 n-chunks
    int b = g & 31, nc = g >> 5;
    int n = nc * 256 + t;
    const float invM = 1.0f / (float)BN_TOTAL;

    if (t < 64) {
        float mn = stats[t * STATS_STRIDE] * invM;
        float var = stats2[t * STATS_STRIDE] * invM - mn * mn;
        smean[t] = mn;
        sinv[t] = rsqrtf(var + EPS_BN);
        sg[t] = gamma[t]; sb[t] = beta[t]; sf[t] = fc_w[t];
    }
    __syncthreads();

    float fb = fc_b[0];
    float p = 0.f;
#pragma unroll
    for (int c = 0; c < 16; c++) {
        float4 o = ((const float4*)obufT)[((size_t)c * B_BATCH + b) * N_NODES + n];
        int d = 4 * c;
        float v;
        v = fmaxf((o.x - smean[d + 0]) * sinv[d + 0] * sg[d + 0] + sb[d + 0], 0.f); p = fmaf(v, sf[d + 0], p);
        v = fmaxf((o.y - smean[d + 1]) * sinv[d + 1] * sg[d + 1] + sb[d + 1], 0.f); p = fmaf(v, sf[d + 1], p);
        v = fmaxf((o.z - smean[d + 2]) * sinv[d + 2] * sg[d + 2] + sb[d + 2], 0.f); p = fmaf(v, sf[d + 2], p);
        v = fmaxf((o.w - smean[d + 3]) * sinv[d + 3] * sg[d + 3] + sb[d + 3], 0.f); p = fmaf(v, sf[d + 3], p);
    }
    out[b * N_NODES + n] = p + fb;
}

// ---------------- launch ----------------------------------------------------
extern "C" void kernel_launch(void* const* d_in, const int* in_sizes, int n_in,
                              void* d_out, int out_size, void* d_ws, size_t ws_size,
                              hipStream_t stream) {
    const float* x     = (const float*)d_in[0];
    const float* emb   = (const float*)d_in[1];
    const float* W     = (const float*)d_in[2];
    const float* Wb    = (const float*)d_in[3];
    const float* a_src = (const float*)d_in[4];
    const float* a_dst = (const float*)d_in[5];
    const float* gamma = (const float*)d_in[6];
    const float* beta  = (const float*)d_in[7];
    const float* fc_w  = (const float*)d_in[8];
    const float* fc_b  = (const float*)d_in[9];
    float* out = (float*)d_out;

    char* ws = (char*)d_ws;
    float* stats   = (float*)(ws + 0);            // 4 KB
    float* stats2  = (float*)(ws + 4096);         // 4 KB
    int*   idxT    = (int*)  (ws + 8192);         // 172032 B
    float* norms   = (float*)(ws + 180224);       // 8 KB
    float* es_embP = (float*)(ws + 188416);       // 8 KB
    float* ed_embP = (float*)(ws + 196608);       // 8 KB
    float* xs2T    = (float*)(ws + 204800);       // 256 KB [b][n]
    float* xd2T    = (float*)(ws + 466944);       // 256 KB [b][n]
    float* alphaT  = (float*)(ws + 729088);       // 5505024 B [b][k][i]
    float* dotM    = (float*)(ws + 6234112);      // 16 MB — aliased with obufT
    float* obufT   = dotM;                        // (dotM dead after k_select)
    // total: 23,011,328 bytes

    k_preg<<<1104, 256, 0, stream>>>(x, W, Wb, a_src, a_dst, emb,
                                     xs2T, xd2T, es_embP, ed_embP, norms,
                                     dotM, stats, stats2);
    k_select<<<N_NODES / 2, 256, 0, stream>>>(dotM, norms, idxT);
    k_alpha<<<256, 256, 0, stream>>>(idxT, xs2T, xd2T, es_embP, ed_embP, alphaT);
    k_msg<<<512, 256, 0, stream>>>(x, W, Wb, idxT, alphaT, emb, obufT, stats, stats2);
    k_out<<<256, 256, 0, stream>>>(obufT, stats, stats2, gamma, beta, fc_w, fc_b, out);
}